// Round 7
// baseline (431.652 us; speedup 1.0000x reference)
//
#include <hip/hip_runtime.h>
#include <hip/hip_bf16.h>
#include <math.h>

#define N_NODES 8192
#define DIN 384
#define DH 512
#define KNB 6
#define NEG_SLOPE 0.01f
#define NSPLIT 4

typedef __attribute__((ext_vector_type(8))) short bf16x8;
typedef __attribute__((ext_vector_type(4))) float f32x4;

__device__ __forceinline__ unsigned short f2bf(float x) {
  unsigned int u = __float_as_uint(x);
  unsigned int r = (u + 0x7fffu + ((u >> 16) & 1u)) >> 16;  // RNE
  return (unsigned short)r;
}
__device__ __forceinline__ float bf2f(unsigned short u) {
  return __uint_as_float(((unsigned int)u) << 16);
}

// ---------------------------------------------------------------------------
// Weight prep: W[K][N] fp32 -> Wt[N][K] bf16, all 6 weights into one pool.
// ---------------------------------------------------------------------------
__global__ __launch_bounds__(256) void prep_weights(
    const float* __restrict__ w0, const float* __restrict__ w1,
    const float* __restrict__ w2, const float* __restrict__ w3,
    const float* __restrict__ w4, const float* __restrict__ w5,
    unsigned short* __restrict__ pool) {
  const int f = blockIdx.x * 256 + threadIdx.x;
  const int E0 = 196608, E1 = 458752, E2 = 720896, E3 = 983040, E4 = 1245184, E5 = 1376256;
  if (f >= E5) return;
  const float* src; int off, Kw, Nw;
  if (f < E0)      { src = w0; off = 0;  Kw = 384; Nw = 512; }
  else if (f < E1) { src = w1; off = E0; Kw = 512; Nw = 512; }
  else if (f < E2) { src = w2; off = E1; Kw = 512; Nw = 512; }
  else if (f < E3) { src = w3; off = E2; Kw = 512; Nw = 512; }
  else if (f < E4) { src = w4; off = E3; Kw = 512; Nw = 512; }
  else             { src = w5; off = E4; Kw = 512; Nw = 256; }
  const int local = f - off;
  const int n = local / Kw, k = local - n * Kw;
  pool[f] = f2bf(src[(size_t)k * Nw + n]);
}

// x_s fp32 -> bf16
__global__ __launch_bounds__(256) void convert_xs(const float* __restrict__ xs,
                                                  unsigned short* __restrict__ out) {
  const size_t i = ((size_t)blockIdx.x * 256 + threadIdx.x) * 4;
  const float4 v = *reinterpret_cast<const float4*>(xs + i);
  ushort4 o;
  o.x = f2bf(v.x); o.y = f2bf(v.y); o.z = f2bf(v.z); o.w = f2bf(v.w);
  *reinterpret_cast<ushort4*>(out + i) = o;
}

// ---------------------------------------------------------------------------
// bf16 MFMA GEMM: C[M,N] = act(A[M,K]bf16 @ Wt[N,K]bf16^T + bias) variants.
// PACKB: bf16 output written in MFMA-fragment-major layout for score kernel.
// ---------------------------------------------------------------------------
template <int ACT, int ACC, int WF32, int WBF16, int PACKB>
__global__ __launch_bounds__(256) void gemm_bf16(
    const unsigned short* __restrict__ A, const unsigned short* __restrict__ Wt,
    const float* __restrict__ bias, float* __restrict__ C,
    unsigned short* __restrict__ Cb, float bscale, int M, int K, int N) {
  __shared__ unsigned short sa[64 * 64];
  __shared__ unsigned short sb[64 * 64];
  const int tid = threadIdx.x;
  const int wave = tid >> 6, lane = tid & 63;
  const int lo16 = lane & 15, hi = lane >> 4;
  const int row0 = blockIdx.y << 6, col0 = blockIdx.x << 6;
  f32x4 acc[4];
#pragma unroll
  for (int rt = 0; rt < 4; ++rt) { acc[rt].x = 0.f; acc[rt].y = 0.f; acc[rt].z = 0.f; acc[rt].w = 0.f; }
  for (int k0 = 0; k0 < K; k0 += 64) {
    __syncthreads();
#pragma unroll
    for (int i = 0; i < 2; ++i) {
      const int c = i * 256 + tid;
      const int r = c >> 3, i8 = c & 7;
      const bf16x8 va = *reinterpret_cast<const bf16x8*>(A + (size_t)(row0 + r) * K + k0 + i8 * 8);
      const bf16x8 vb = *reinterpret_cast<const bf16x8*>(Wt + (size_t)(col0 + r) * K + k0 + i8 * 8);
      const int byte = r * 128 + ((i8 * 16) ^ ((r & 7) << 4));
      *reinterpret_cast<bf16x8*>(reinterpret_cast<char*>(sa) + byte) = va;
      *reinterpret_cast<bf16x8*>(reinterpret_cast<char*>(sb) + byte) = vb;
    }
    __syncthreads();
#pragma unroll
    for (int kk2 = 0; kk2 < 2; ++kk2) {
      const int col = wave * 16 + lo16;
      const int bbyte = col * 128 + (((kk2 << 6) + (hi << 4)) ^ ((col & 7) << 4));
      const bf16x8 bf = *reinterpret_cast<const bf16x8*>(reinterpret_cast<const char*>(sb) + bbyte);
#pragma unroll
      for (int rt = 0; rt < 4; ++rt) {
        const int row = rt * 16 + lo16;
        const int abyte = row * 128 + (((kk2 << 6) + (hi << 4)) ^ ((row & 7) << 4));
        const bf16x8 af = *reinterpret_cast<const bf16x8*>(reinterpret_cast<const char*>(sa) + abyte);
        acc[rt] = __builtin_amdgcn_mfma_f32_16x16x32_bf16(af, bf, acc[rt], 0, 0, 0);
      }
    }
  }
  const int colg = col0 + wave * 16 + lo16;
  const float bv = bias[colg];
#pragma unroll
  for (int rt = 0; rt < 4; ++rt) {
#pragma unroll
    for (int j = 0; j < 4; ++j) {
      const int r = row0 + rt * 16 + hi * 4 + j;
      float v = acc[rt][j] + bv;
      if (ACT) v = v > 0.f ? v : NEG_SLOPE * v;
      if (ACC) v += C[(size_t)r * N + colg];
      if (WF32) C[(size_t)r * N + colg] = v;
      if (WBF16) {
        if (PACKB) {
          const size_t idx = (size_t)(r >> 4) * 8192 + (size_t)(colg >> 5) * 512 +
                             (size_t)((((colg & 31) >> 3) * 16 + (r & 15)) * 8) + (colg & 7);
          Cb[idx] = f2bf(v * bscale);
        } else {
          Cb[(size_t)r * N + colg] = f2bf(v * bscale);
        }
      }
    }
  }
}

// ---------------------------------------------------------------------------
// Column sums of X[8192 x 512]
// ---------------------------------------------------------------------------
__global__ __launch_bounds__(256) void colsum_kernel(const float* __restrict__ X,
                                                     float* __restrict__ cs) {
  const int tid = threadIdx.x;
  float s0 = 0.f, s1 = 0.f;
  const int r0 = blockIdx.x * 128;
  for (int r = r0; r < r0 + 128; ++r) {
    s0 += X[(size_t)r * DH + tid];
    s1 += X[(size_t)r * DH + tid + 256];
  }
  atomicAdd(&cs[tid], s0);
  atomicAdd(&cs[tid + 256], s1);
}

// x = (x + colmean) * 0.5 ; also emit bf16 copy
__global__ __launch_bounds__(256) void mix_kernel(float* __restrict__ X,
                                                  const float* __restrict__ cs,
                                                  unsigned short* __restrict__ Xb) {
  const size_t gid = (size_t)blockIdx.x * 256 + threadIdx.x;
  const int c4 = ((int)gid & 127) << 2;
  float4 x = *reinterpret_cast<float4*>(X + gid * 4);
  const float inv = 1.f / 8192.f;
  x.x = (x.x + cs[c4 + 0] * inv) * 0.5f;
  x.y = (x.y + cs[c4 + 1] * inv) * 0.5f;
  x.z = (x.z + cs[c4 + 2] * inv) * 0.5f;
  x.w = (x.w + cs[c4 + 3] * inv) * 0.5f;
  *reinterpret_cast<float4*>(X + gid * 4) = x;
  ushort4 o;
  o.x = f2bf(x.x); o.y = f2bf(x.y); o.z = f2bf(x.z); o.w = f2bf(x.w);
  *reinterpret_cast<ushort4*>(Xb + gid * 4) = o;
}

// ---------------------------------------------------------------------------
// MFMA scoring + streaming top-6, v5: v4 + A-fragment register double-buffer.
// The 8 ds_read_b128 for kk+1's A-frags are issued BEFORE kk's 32 MFMAs, so
// LDS latency hides under MFMA issue (A-frags depend only on kk, so the
// (kk+1)&15 prefetch is uniform across jt). B stays 1-deep (covered: issued
// one full iteration (~310 SIMD-cyc) ahead of use > L2 latency).
// ---------------------------------------------------------------------------
__global__ __launch_bounds__(512, 2) void score_topk_v3(
    const unsigned short* __restrict__ EHb, const unsigned short* __restrict__ ETp,
    float* __restrict__ tkv, int* __restrict__ tki) {
  __shared__ unsigned short sa[128 * 512];  // 131072 B, swizzled A
  __shared__ float swb[8][8 * 68];          // 17408 B, per-wave score slices
  const int tid = threadIdx.x;
  const int wave = tid >> 6, lane = tid & 63;
  const int lo16 = lane & 15, hi = lane >> 4;
  const int bid = blockIdx.x;
  const int split = (bid & 7) >> 1;
  const int rowblk = ((bid >> 3) << 1) | (bid & 1);
  const int grow0 = rowblk << 7;       // 128 rows/block
  const int colbase0 = split << 11;    // 2048 cols/split

  // stage A rows [grow0, grow0+128) swizzled
#pragma unroll
  for (int i = 0; i < 16; ++i) {
    const int c = i * 512 + tid;
    const int row = c >> 6, i8 = c & 63;
    const bf16x8 v = *reinterpret_cast<const bf16x8*>(
        EHb + (size_t)(grow0 + row) * DH + i8 * 8);
    const int byte = row * 1024 + ((i8 * 16) ^ ((row & 7) << 4));
    *reinterpret_cast<bf16x8*>(reinterpret_cast<char*>(sa) + byte) = v;
  }
  __syncthreads();

  float tv[2][6];
  int ti[2][6];
#pragma unroll
  for (int a = 0; a < 2; ++a)
#pragma unroll
    for (int s = 0; s < 6; ++s) { tv[a][s] = -3.4e38f; ti[a][s] = 0; }

  float* sw = swb[wave];

  // prologue: jt=0, kk=0 B-frags (coalesced from packed layout)
  bf16x8 bcur[4];
  {
    const int jg0 = (colbase0 + wave * 64) >> 4;
#pragma unroll
    for (int ct = 0; ct < 4; ++ct)
      bcur[ct] = *reinterpret_cast<const bf16x8*>(
          ETp + (size_t)(jg0 + ct) * 8192 + lane * 8);
  }
  // prologue: kk=0 A-frags from LDS
  bf16x8 acur[8];
#pragma unroll
  for (int rt = 0; rt < 8; ++rt) {
    const int row = rt * 16 + lo16;
    acur[rt] = *reinterpret_cast<const bf16x8*>(
        reinterpret_cast<const char*>(sa) + row * 1024 + ((hi << 4) ^ ((row & 7) << 4)));
  }

  for (int jt = 0; jt < 4; ++jt) {
    const int wcol0 = colbase0 + jt * 512 + wave * 64;
    const int jgbase = wcol0 >> 4;
    f32x4 acc[8][4];
#pragma unroll
    for (int rt = 0; rt < 8; ++rt)
#pragma unroll
      for (int ct = 0; ct < 4; ++ct) {
        acc[rt][ct].x = 0.f; acc[rt][ct].y = 0.f; acc[rt][ct].z = 0.f; acc[rt][ct].w = 0.f;
      }
#pragma unroll
    for (int kk = 0; kk < 16; ++kk) {
      // B prefetch (1-deep)
      bf16x8 bnxt[4];
      if (kk < 15) {
#pragma unroll
        for (int ct = 0; ct < 4; ++ct)
          bnxt[ct] = *reinterpret_cast<const bf16x8*>(
              ETp + (size_t)(jgbase + ct) * 8192 + (kk + 1) * 512 + lane * 8);
      } else {
        const int jtn = (jt == 3) ? 3 : (jt + 1);
        const int jgn = (colbase0 + jtn * 512 + wave * 64) >> 4;
#pragma unroll
        for (int ct = 0; ct < 4; ++ct)
          bnxt[ct] = *reinterpret_cast<const bf16x8*>(
              ETp + (size_t)(jgn + ct) * 8192 + lane * 8);
      }
      // A prefetch for (kk+1)&15 — issued before the MFMAs consume acur
      bf16x8 anxt[8];
      {
        const int kn = (kk + 1) & 15;
        const int inner = (kn << 6) + (hi << 4);
#pragma unroll
        for (int rt = 0; rt < 8; ++rt) {
          const int row = rt * 16 + lo16;
          anxt[rt] = *reinterpret_cast<const bf16x8*>(
              reinterpret_cast<const char*>(sa) + row * 1024 + (inner ^ ((row & 7) << 4)));
        }
      }
      // MFMAs on current A/B register sets
#pragma unroll
      for (int rt = 0; rt < 8; ++rt)
#pragma unroll
        for (int ct = 0; ct < 4; ++ct)
          acc[rt][ct] = __builtin_amdgcn_mfma_f32_16x16x32_bf16(acur[rt], bcur[ct], acc[rt][ct], 0, 0, 0);
#pragma unroll
      for (int ct = 0; ct < 4; ++ct) bcur[ct] = bnxt[ct];
#pragma unroll
      for (int rt = 0; rt < 8; ++rt) acur[rt] = anxt[rt];
    }
    // dump/scan: 16 passes of (a row-half, ct, h col-half of frag)
#pragma unroll
    for (int a = 0; a < 2; ++a) {
#pragma unroll
      for (int ct = 0; ct < 4; ++ct) {
#pragma unroll
        for (int h = 0; h < 2; ++h) {
          if ((lo16 >> 3) == h) {
#pragma unroll
            for (int rtl = 0; rtl < 4; ++rtl)
              *reinterpret_cast<f32x4*>(sw + (lo16 & 7) * 68 + rtl * 16 + hi * 4) =
                  acc[a * 4 + rtl][ct];
          }
          asm volatile("s_waitcnt lgkmcnt(0)" ::: "memory");
#pragma unroll
          for (int cc = 0; cc < 8; ++cc) {
            const float v = sw[cc * 68 + lane];
            const int col = wcol0 + ct * 16 + h * 8 + cc;
            if (v > tv[a][5]) {
              tv[a][5] = v; ti[a][5] = col;
#pragma unroll
              for (int p = 5; p > 0; --p) {
                if (tv[a][p] > tv[a][p - 1]) {
                  float tvt = tv[a][p]; tv[a][p] = tv[a][p - 1]; tv[a][p - 1] = tvt;
                  int tit = ti[a][p]; ti[a][p] = ti[a][p - 1]; ti[a][p - 1] = tit;
                }
              }
            }
          }
          asm volatile("s_waitcnt lgkmcnt(0)" ::: "memory");
        }
      }
    }
  }
  __syncthreads();
  // merge: reuse A region. mv[128 rows][8 waves][6] + mi
  float* mv = reinterpret_cast<float*>(sa);
  int* mi = reinterpret_cast<int*>(mv + 128 * 8 * 6);
#pragma unroll
  for (int a = 0; a < 2; ++a) {
    const int row = a * 64 + lane;
#pragma unroll
    for (int s = 0; s < 6; ++s) {
      mv[(row * 8 + wave) * 6 + s] = tv[a][s];
      mi[(row * 8 + wave) * 6 + s] = ti[a][s];
    }
  }
  __syncthreads();
  if (tid < 128) {
    int pq[8] = {0, 0, 0, 0, 0, 0, 0, 0};
    const int base = (split * N_NODES + grow0 + tid) * 6;
    for (int s = 0; s < 6; ++s) {
      float best = -3.4e38f;
      int bi = 0x7fffffff, bq = 0;
#pragma unroll
      for (int q = 0; q < 8; ++q) {
        if (pq[q] < 6) {
          const float v = mv[(tid * 8 + q) * 6 + pq[q]];
          const int ix = mi[(tid * 8 + q) * 6 + pq[q]];
          if (v > best || (v == best && ix < bi)) { best = v; bi = ix; bq = q; }
        }
      }
      tkv[base + s] = best;
      tki[base + s] = bi;
#pragma unroll
      for (int q = 0; q < 8; ++q) pq[q] += (bq == q) ? 1 : 0;
    }
  }
}

// merge the 4 j-split top-6 lists into final top-6
__global__ __launch_bounds__(256) void merge_topk4(const float* __restrict__ tkv,
                                                   const int* __restrict__ tki,
                                                   float* __restrict__ fw,
                                                   int* __restrict__ fi) {
  const int n = blockIdx.x * 256 + threadIdx.x;
  int pq[NSPLIT] = {0, 0, 0, 0};
  for (int s = 0; s < 6; ++s) {
    float best = -3.4e38f;
    int bi = 0x7fffffff, bq = 0;
#pragma unroll
    for (int q = 0; q < NSPLIT; ++q) {
      if (pq[q] < 6) {
        const float v = tkv[((size_t)q * N_NODES + n) * 6 + pq[q]];
        const int ix = tki[((size_t)q * N_NODES + n) * 6 + pq[q]];
        if (v > best || (v == best && ix < bi)) { best = v; bi = ix; bq = q; }
      }
    }
    fw[n * 6 + s] = best;
    fi[n * 6 + s] = bi;
#pragma unroll
    for (int q = 0; q < NSPLIT; ++q) pq[q] += (bq == q) ? 1 : 0;
  }
}

// ---------------------------------------------------------------------------
// Per-node neighbor aggregation; outputs Ub, Vb in bf16.
// ---------------------------------------------------------------------------
__global__ __launch_bounds__(256) void agg_kernel(const float* __restrict__ EH,
                                                  const float* __restrict__ ET,
                                                  const float* __restrict__ fw,
                                                  const int* __restrict__ fi,
                                                  unsigned short* __restrict__ Ub,
                                                  unsigned short* __restrict__ Vb) {
  __shared__ float sNb[KNB][DH];
  __shared__ float sred[4][8];
  __shared__ float ska[8];
  const int node = blockIdx.x;
  const int tid = threadIdx.x;
  float w[KNB];
  int idx[KNB];
#pragma unroll
  for (int k = 0; k < KNB; ++k) {
    w[k] = fw[node * KNB + k];
    idx[k] = fi[node * KNB + k];
  }
  float mx = w[0];
#pragma unroll
  for (int k = 1; k < KNB; ++k) mx = fmaxf(mx, w[k]);
  float pk[KNB];
  float se = 0.f;
#pragma unroll
  for (int k = 0; k < KNB; ++k) { pk[k] = expf(w[k] - mx); se += pk[k]; }
  const float inv_se = 1.f / se;
#pragma unroll
  for (int k = 0; k < KNB; ++k) pk[k] *= inv_se;
  for (int e = tid; e < KNB * DH; e += 256) {
    int k = e >> 9, d = e & 511;
    sNb[k][d] = ET[(size_t)idx[k] * DH + d];
  }
  __syncthreads();
  float eh[2];
  eh[0] = EH[(size_t)node * DH + tid];
  eh[1] = EH[(size_t)node * DH + tid + 256];
  float ka[KNB] = {0, 0, 0, 0, 0, 0};
#pragma unroll
  for (int t = 0; t < 2; ++t) {
    const int d = tid + t * 256;
    const float e_ = eh[t];
#pragma unroll
    for (int k = 0; k < KNB; ++k) {
      float Nb = sNb[k][d];
      float ehr = pk[k] * Nb + (1.f - pk[k]) * e_;
      float g = tanhf(e_ + ehr);
      ka[k] = fmaf(Nb, g, ka[k]);
    }
  }
#pragma unroll
  for (int k = 0; k < KNB; ++k) {
    float v = ka[k];
#pragma unroll
    for (int off = 32; off > 0; off >>= 1) v += __shfl_down(v, off, 64);
    if ((tid & 63) == 0) sred[tid >> 6][k] = v;
  }
  __syncthreads();
  if (tid < KNB) ska[tid] = sred[0][tid] + sred[1][tid] + sred[2][tid] + sred[3][tid];
  __syncthreads();
  float kav[KNB];
#pragma unroll
  for (int k = 0; k < KNB; ++k) kav[k] = ska[k];
  float kmx = kav[0];
#pragma unroll
  for (int k = 1; k < KNB; ++k) kmx = fmaxf(kmx, kav[k]);
  float kp[KNB];
  float ks = 0.f;
#pragma unroll
  for (int k = 0; k < KNB; ++k) { kp[k] = expf(kav[k] - kmx); ks += kp[k]; }
  const float inv_ks = 1.f / ks;
#pragma unroll
  for (int k = 0; k < KNB; ++k) kp[k] *= inv_ks;
#pragma unroll
  for (int t = 0; t < 2; ++t) {
    const int d = tid + t * 256;
    float eNh = 0.f;
#pragma unroll
    for (int k = 0; k < KNB; ++k) eNh = fmaf(kp[k], sNb[k][d], eNh);
    const float e_ = eh[t];
    Ub[(size_t)node * DH + d] = f2bf(e_ + eNh);
    Vb[(size_t)node * DH + d] = f2bf(e_ * eNh);
  }
}

// a[n] = dot(hid_bf16[n], att2_w) + att2_b ; one wave per node
__global__ __launch_bounds__(256) void att_dot(const unsigned short* __restrict__ HIDb,
                                               const float* __restrict__ w2,
                                               const float* __restrict__ b2,
                                               float* __restrict__ a) {
  const int wid = threadIdx.x >> 6, lane = threadIdx.x & 63;
  const int node = blockIdx.x * 4 + wid;
  const ushort4 h4 = *reinterpret_cast<const ushort4*>(HIDb + (size_t)node * 256 + lane * 4);
  const float4 w4 = *reinterpret_cast<const float4*>(w2 + lane * 4);
  float s = bf2f(h4.x) * w4.x + bf2f(h4.y) * w4.y + bf2f(h4.z) * w4.z + bf2f(h4.w) * w4.w;
#pragma unroll
  for (int off = 32; off > 0; off >>= 1) s += __shfl_down(s, off, 64);
  if (lane == 0) a[node] = s + b2[0];
}

// global softmax stats over a[8192]
__global__ __launch_bounds__(1024) void softmax_stats(const float* __restrict__ a,
                                                      float* __restrict__ st) {
  __shared__ float red[16];
  __shared__ float bc;
  const int tid = threadIdx.x;
  float mx = -3.4e38f;
  for (int i = tid; i < N_NODES; i += 1024) mx = fmaxf(mx, a[i]);
#pragma unroll
  for (int off = 32; off > 0; off >>= 1) mx = fmaxf(mx, __shfl_xor(mx, off, 64));
  if ((tid & 63) == 0) red[tid >> 6] = mx;
  __syncthreads();
  if (tid == 0) {
    float m = red[0];
    for (int i = 1; i < 16; ++i) m = fmaxf(m, red[i]);
    bc = m;
  }
  __syncthreads();
  const float gm = bc;
  float se = 0.f;
  for (int i = tid; i < N_NODES; i += 1024) se += expf(a[i] - gm);
#pragma unroll
  for (int off = 32; off > 0; off >>= 1) se += __shfl_xor(se, off, 64);
  if ((tid & 63) == 0) red[tid >> 6] = se;
  __syncthreads();
  if (tid == 0) {
    float s = 0.f;
    for (int i = 0; i < 16; ++i) s += red[i];
    st[0] = gm;
    st[1] = s;
  }
}

// h[c] = sum_n softmax(a)_n * emb_bf16[n][c]
__global__ __launch_bounds__(256) void readout(const unsigned short* __restrict__ EMBb,
                                               const float* __restrict__ a,
                                               const float* __restrict__ st,
                                               float* __restrict__ h) {
  __shared__ float sacc[4][64];
  const int tid = threadIdx.x;
  const int c = (blockIdx.x << 6) + (tid & 63);
  const int rsub = tid >> 6;
  const float mx = st[0], inv_se = 1.f / st[1];
  const int r0 = blockIdx.y << 8;
  float acc = 0.f;
  for (int i = 0; i < 64; ++i) {
    const int r = r0 + (i << 2) + rsub;
    const float g = expf(a[r] - mx);
    acc = fmaf(g, bf2f(EMBb[(size_t)r * DH + c]), acc);
  }
  sacc[rsub][tid & 63] = acc * inv_se;
  __syncthreads();
  if (rsub == 0) {
    float t = sacc[0][tid] + sacc[1][tid] + sacc[2][tid] + sacc[3][tid];
    atomicAdd(&h[c], t);
  }
}

// layernorm + final fc -> 2 logits
__global__ __launch_bounds__(512) void finalize(const float* __restrict__ h,
                                                const float* __restrict__ ln_g,
                                                const float* __restrict__ ln_b,
                                                const float* __restrict__ fc_w,
                                                const float* __restrict__ fc_b,
                                                float* __restrict__ out) {
  __shared__ float red0[8];
  __shared__ float red1[8];
  __shared__ float bc[2];
  const int tid = threadIdx.x;
  const int wid = tid >> 6, lane = tid & 63;
  const float v = h[tid];
  float s = v;
#pragma unroll
  for (int off = 32; off > 0; off >>= 1) s += __shfl_xor(s, off, 64);
  if (lane == 0) red0[wid] = s;
  __syncthreads();
  if (tid == 0) {
    float t = 0.f;
    for (int i = 0; i < 8; ++i) t += red0[i];
    bc[0] = t * (1.f / 512.f);
  }
  __syncthreads();
  const float mu = bc[0];
  const float dv = v - mu;
  s = dv * dv;
#pragma unroll
  for (int off = 32; off > 0; off >>= 1) s += __shfl_xor(s, off, 64);
  if (lane == 0) red0[wid] = s;
  __syncthreads();
  if (tid == 0) {
    float t = 0.f;
    for (int i = 0; i < 8; ++i) t += red0[i];
    bc[1] = t * (1.f / 512.f);
  }
  __syncthreads();
  const float var = bc[1];
  const float hn = dv / sqrtf(var + 1e-5f) * ln_g[tid] + ln_b[tid];
  float l0 = hn * fc_w[tid * 2 + 0];
  float l1 = hn * fc_w[tid * 2 + 1];
#pragma unroll
  for (int off = 32; off > 0; off >>= 1) {
    l0 += __shfl_xor(l0, off, 64);
    l1 += __shfl_xor(l1, off, 64);
  }
  if (lane == 0) { red0[wid] = l0; red1[wid] = l1; }
  __syncthreads();
  if (tid == 0) {
    float t0 = 0.f, t1 = 0.f;
    for (int i = 0; i < 8; ++i) { t0 += red0[i]; t1 += red1[i]; }
    out[0] = t0 + fc_b[0];
    out[1] = t1 + fc_b[1];
  }
}

// ---------------------------------------------------------------------------
extern "C" void kernel_launch(void* const* d_in, const int* in_sizes, int n_in,
                              void* d_out, int out_size, void* d_ws, size_t ws_size,
                              hipStream_t stream) {
  const float* x_s    = (const float*)d_in[0];
  const float* fc1_w  = (const float*)d_in[1];
  const float* fc1_b  = (const float*)d_in[2];
  const float* wh_w   = (const float*)d_in[3];
  const float* wh_b   = (const float*)d_in[4];
  const float* wt_w   = (const float*)d_in[5];
  const float* wt_b   = (const float*)d_in[6];
  const float* l1_w   = (const float*)d_in[7];
  const float* l1_b   = (const float*)d_in[8];
  const float* l2_w   = (const float*)d_in[9];
  const float* l2_b   = (const float*)d_in[10];
  const float* att1_w = (const float*)d_in[11];
  const float* att1_b = (const float*)d_in[12];
  const float* att2_w = (const float*)d_in[13];
  const float* att2_b = (const float*)d_in[14];
  const float* ln_g   = (const float*)d_in[15];
  const float* ln_b   = (const float*)d_in[16];
  const float* fc_w   = (const float*)d_in[17];
  const float* fc_b   = (const float*)d_in[18];

  float* ws = (float*)d_ws;
  const size_t BIG = (size_t)N_NODES * DH;  // 4,194,304
  float* B1 = ws;
  float* B2 = ws + BIG;
  unsigned short* R1 = (unsigned short*)(ws + 2 * BIG);  // xsb -> EHb -> Ub -> hidb
  unsigned short* R2 = R1 + BIG;                          // xb -> Vb
  unsigned short* R3 = R2 + BIG;                          // ETp (packed) -> embb
  unsigned short* WT = R3 + BIG;                          // transposed bf16 weights
  float* tail = (float*)(WT + 1376256);
  float* tkv    = tail;                          // 4*8192*6
  int*   tki    = (int*)(tkv + NSPLIT * N_NODES * 6);
  float* fwv    = (float*)(tki + NSPLIT * N_NODES * 6);
  int*   fiv    = (int*)(fwv + N_NODES * 6);
  float* colsum = (float*)(fiv + N_NODES * 6);
  float* av     = colsum + DH;
  float* stats  = av + N_NODES;
  float* hbuf   = stats + 16;

  unsigned short* fc1t  = WT + 0;
  unsigned short* wht   = WT + 196608;
  unsigned short* wtt   = WT + 458752;
  unsigned short* l1t   = WT + 720896;
  unsigned short* l2t   = WT + 983040;
  unsigned short* att1t = WT + 1245184;

  const float kscale = 0.044194173824159216f;  // 512^-0.5

  // 0. prep
  prep_weights<<<5376, 256, 0, stream>>>(fc1_w, wh_w, wt_w, l1_w, l2_w, att1_w, WT);
  convert_xs<<<3072, 256, 0, stream>>>(x_s, R1);
  // 1. x = lrelu(xsb @ fc1t^T + b) -> B1
  gemm_bf16<1, 0, 1, 0, 0><<<dim3(8, 128), 256, 0, stream>>>(
      R1, fc1t, fc1_b, B1, nullptr, 1.f, N_NODES, DIN, DH);
  // 2. mean-mix -> B1 fp32 + xb bf16 (R2)
  hipMemsetAsync(colsum, 0, DH * sizeof(float), stream);
  colsum_kernel<<<64, 256, 0, stream>>>(B1, colsum);
  mix_kernel<<<4096, 256, 0, stream>>>(B1, colsum, R2);
  // 3. e_h -> B1 + EHb*scale (R1, row-major); e_t -> B2 + ETp (R3, frag-packed)
  gemm_bf16<0, 0, 1, 1, 0><<<dim3(8, 128), 256, 0, stream>>>(
      R2, wht, wh_b, B1, R1, kscale, N_NODES, DH, DH);
  gemm_bf16<0, 0, 1, 1, 1><<<dim3(8, 128), 256, 0, stream>>>(
      R2, wtt, wt_b, B2, R3, 1.f, N_NODES, DH, DH);
  // 4. scoring v5 (A-dbuf) + merge
  score_topk_v3<<<256, 512, 0, stream>>>(R1, R3, tkv, tki);
  merge_topk4<<<32, 256, 0, stream>>>(tkv, tki, fwv, fiv);
  // 5. aggregation -> Ub (R1), Vb (R2)
  agg_kernel<<<N_NODES, 256, 0, stream>>>(B1, B2, fwv, fiv, R1, R2);
  // 6. emb = lrelu(Ub@l1+b1) + lrelu(Vb@l2+b2) -> B1 fp32, embb (R3)
  gemm_bf16<1, 0, 1, 0, 0><<<dim3(8, 128), 256, 0, stream>>>(
      R1, l1t, l1_b, B1, nullptr, 1.f, N_NODES, DH, DH);
  gemm_bf16<1, 1, 0, 1, 0><<<dim3(8, 128), 256, 0, stream>>>(
      R2, l2t, l2_b, B1, R3, 1.f, N_NODES, DH, DH);
  // 7. attention readout
  gemm_bf16<1, 0, 0, 1, 0><<<dim3(4, 128), 256, 0, stream>>>(
      R3, att1t, att1_b, B2, R1, 1.f, N_NODES, DH, 256);
  att_dot<<<2048, 256, 0, stream>>>(R1, att2_w, att2_b, av);
  softmax_stats<<<1, 1024, 0, stream>>>(av, stats);
  hipMemsetAsync(hbuf, 0, DH * sizeof(float), stream);
  readout<<<dim3(8, 32), 256, 0, stream>>>(R3, av, stats, hbuf);
  // 8. layernorm + logits
  finalize<<<1, 512, 0, stream>>>(hbuf, ln_g, ln_b, fc_w, fc_b, (float*)d_out);
}

// Round 8
// 406.472 us; speedup vs baseline: 1.0619x; 1.0619x over previous
//
#include <hip/hip_runtime.h>
#include <hip/hip_bf16.h>
#include <math.h>

#define N_NODES 8192
#define DIN 384
#define DH 512
#define KNB 6
#define NEG_SLOPE 0.01f
#define NSPLIT 4

typedef __attribute__((ext_vector_type(8))) short bf16x8;
typedef __attribute__((ext_vector_type(4))) float f32x4;

__device__ __forceinline__ unsigned short f2bf(float x) {
  unsigned int u = __float_as_uint(x);
  unsigned int r = (u + 0x7fffu + ((u >> 16) & 1u)) >> 16;  // RNE
  return (unsigned short)r;
}
__device__ __forceinline__ float bf2f(unsigned short u) {
  return __uint_as_float(((unsigned int)u) << 16);
}

// ---------------------------------------------------------------------------
// Weight prep: W[K][N] fp32 -> Wt[N][K] bf16, all 6 weights into one pool.
// ---------------------------------------------------------------------------
__global__ __launch_bounds__(256) void prep_weights(
    const float* __restrict__ w0, const float* __restrict__ w1,
    const float* __restrict__ w2, const float* __restrict__ w3,
    const float* __restrict__ w4, const float* __restrict__ w5,
    unsigned short* __restrict__ pool) {
  const int f = blockIdx.x * 256 + threadIdx.x;
  const int E0 = 196608, E1 = 458752, E2 = 720896, E3 = 983040, E4 = 1245184, E5 = 1376256;
  if (f >= E5) return;
  const float* src; int off, Kw, Nw;
  if (f < E0)      { src = w0; off = 0;  Kw = 384; Nw = 512; }
  else if (f < E1) { src = w1; off = E0; Kw = 512; Nw = 512; }
  else if (f < E2) { src = w2; off = E1; Kw = 512; Nw = 512; }
  else if (f < E3) { src = w3; off = E2; Kw = 512; Nw = 512; }
  else if (f < E4) { src = w4; off = E3; Kw = 512; Nw = 512; }
  else             { src = w5; off = E4; Kw = 512; Nw = 256; }
  const int local = f - off;
  const int n = local / Kw, k = local - n * Kw;
  pool[f] = f2bf(src[(size_t)k * Nw + n]);
}

// x_s fp32 -> bf16
__global__ __launch_bounds__(256) void convert_xs(const float* __restrict__ xs,
                                                  unsigned short* __restrict__ out) {
  const size_t i = ((size_t)blockIdx.x * 256 + threadIdx.x) * 4;
  const float4 v = *reinterpret_cast<const float4*>(xs + i);
  ushort4 o;
  o.x = f2bf(v.x); o.y = f2bf(v.y); o.z = f2bf(v.z); o.w = f2bf(v.w);
  *reinterpret_cast<ushort4*>(out + i) = o;
}

// ---------------------------------------------------------------------------
// 128x128-tile bf16 MFMA GEMM (single A, single W). 4 waves, each owns a
// 64x64 quadrant: per 32-k step 8 ds_read_b128 -> 16 MFMAs.
// ---------------------------------------------------------------------------
template <int ACT, int WF32, int WBF16>
__global__ __launch_bounds__(256) void gemm128(
    const unsigned short* __restrict__ A, const unsigned short* __restrict__ Wt,
    const float* __restrict__ bias, float* __restrict__ C,
    unsigned short* __restrict__ Cb, int K, int N) {
  __shared__ unsigned short sa[128 * 64];
  __shared__ unsigned short sb[128 * 64];
  const int tid = threadIdx.x;
  const int wave = tid >> 6, lane = tid & 63;
  const int lo16 = lane & 15, hi = lane >> 4;
  const int wr = (wave >> 1) << 6, wc = (wave & 1) << 6;
  const int row0 = blockIdx.y << 7, col0 = blockIdx.x << 7;
  f32x4 acc[4][4];
#pragma unroll
  for (int rt = 0; rt < 4; ++rt)
#pragma unroll
    for (int ct = 0; ct < 4; ++ct) { acc[rt][ct].x = 0.f; acc[rt][ct].y = 0.f; acc[rt][ct].z = 0.f; acc[rt][ct].w = 0.f; }
  for (int k0 = 0; k0 < K; k0 += 64) {
    __syncthreads();
#pragma unroll
    for (int i = 0; i < 4; ++i) {
      const int c = i * 256 + tid;  // 0..1023
      const int r = c >> 3, i8 = c & 7;
      const bf16x8 va = *reinterpret_cast<const bf16x8*>(A + (size_t)(row0 + r) * K + k0 + i8 * 8);
      const bf16x8 vb = *reinterpret_cast<const bf16x8*>(Wt + (size_t)(col0 + r) * K + k0 + i8 * 8);
      const int byte = r * 128 + ((i8 * 16) ^ ((r & 7) << 4));
      *reinterpret_cast<bf16x8*>(reinterpret_cast<char*>(sa) + byte) = va;
      *reinterpret_cast<bf16x8*>(reinterpret_cast<char*>(sb) + byte) = vb;
    }
    __syncthreads();
#pragma unroll
    for (int kk2 = 0; kk2 < 2; ++kk2) {
      const int inner = (kk2 << 6) + (hi << 4);
      bf16x8 af[4], bf[4];
#pragma unroll
      for (int t = 0; t < 4; ++t) {
        const int row = wr + t * 16 + lo16;
        af[t] = *reinterpret_cast<const bf16x8*>(reinterpret_cast<const char*>(sa) + row * 128 + (inner ^ ((row & 7) << 4)));
        const int col = wc + t * 16 + lo16;
        bf[t] = *reinterpret_cast<const bf16x8*>(reinterpret_cast<const char*>(sb) + col * 128 + (inner ^ ((col & 7) << 4)));
      }
#pragma unroll
      for (int rt = 0; rt < 4; ++rt)
#pragma unroll
        for (int ct = 0; ct < 4; ++ct)
          acc[rt][ct] = __builtin_amdgcn_mfma_f32_16x16x32_bf16(af[rt], bf[ct], acc[rt][ct], 0, 0, 0);
    }
  }
#pragma unroll
  for (int ct = 0; ct < 4; ++ct) {
    const int colg = col0 + wc + ct * 16 + lo16;
    const float bv = bias[colg];
#pragma unroll
    for (int rt = 0; rt < 4; ++rt) {
#pragma unroll
      for (int j = 0; j < 4; ++j) {
        const int r = row0 + wr + rt * 16 + hi * 4 + j;
        float v = acc[rt][ct][j] + bv;
        if (ACT) v = v > 0.f ? v : NEG_SLOPE * v;
        if (WF32) C[(size_t)r * N + colg] = v;
        if (WBF16) Cb[(size_t)r * N + colg] = f2bf(v);
      }
    }
  }
}

// ---------------------------------------------------------------------------
// Fused e_h/e_t GEMM: same A (xb), two weight tiles. Outputs:
//   e_h: fp32 (B1) + bf16*kscale row-major (EHb)
//   e_t: fp32 (B2) + bf16 frag-packed (ETp) for the score kernel.
// ---------------------------------------------------------------------------
__global__ __launch_bounds__(256) void gemm128_ehet(
    const unsigned short* __restrict__ A,
    const unsigned short* __restrict__ W1, const unsigned short* __restrict__ W2,
    const float* __restrict__ b1, const float* __restrict__ b2,
    float* __restrict__ C1, unsigned short* __restrict__ EHb,
    float* __restrict__ C2, unsigned short* __restrict__ ETp, float kscale) {
  __shared__ unsigned short sa[128 * 64];
  __shared__ unsigned short sb1[128 * 64];
  __shared__ unsigned short sb2[128 * 64];
  const int tid = threadIdx.x;
  const int wave = tid >> 6, lane = tid & 63;
  const int lo16 = lane & 15, hi = lane >> 4;
  const int wr = (wave >> 1) << 6, wc = (wave & 1) << 6;
  const int row0 = blockIdx.y << 7, col0 = blockIdx.x << 7;
  f32x4 au[4][4], av[4][4];
#pragma unroll
  for (int rt = 0; rt < 4; ++rt)
#pragma unroll
    for (int ct = 0; ct < 4; ++ct) {
      au[rt][ct].x = 0.f; au[rt][ct].y = 0.f; au[rt][ct].z = 0.f; au[rt][ct].w = 0.f;
      av[rt][ct].x = 0.f; av[rt][ct].y = 0.f; av[rt][ct].z = 0.f; av[rt][ct].w = 0.f;
    }
  for (int k0 = 0; k0 < DH; k0 += 64) {
    __syncthreads();
#pragma unroll
    for (int i = 0; i < 4; ++i) {
      const int c = i * 256 + tid;
      const int r = c >> 3, i8 = c & 7;
      const int byte = r * 128 + ((i8 * 16) ^ ((r & 7) << 4));
      *reinterpret_cast<bf16x8*>(reinterpret_cast<char*>(sa) + byte) =
          *reinterpret_cast<const bf16x8*>(A + (size_t)(row0 + r) * DH + k0 + i8 * 8);
      *reinterpret_cast<bf16x8*>(reinterpret_cast<char*>(sb1) + byte) =
          *reinterpret_cast<const bf16x8*>(W1 + (size_t)(col0 + r) * DH + k0 + i8 * 8);
      *reinterpret_cast<bf16x8*>(reinterpret_cast<char*>(sb2) + byte) =
          *reinterpret_cast<const bf16x8*>(W2 + (size_t)(col0 + r) * DH + k0 + i8 * 8);
    }
    __syncthreads();
#pragma unroll
    for (int kk2 = 0; kk2 < 2; ++kk2) {
      const int inner = (kk2 << 6) + (hi << 4);
      bf16x8 af[4], bf1[4], bf2[4];
#pragma unroll
      for (int t = 0; t < 4; ++t) {
        const int row = wr + t * 16 + lo16;
        const int aoff = row * 128 + (inner ^ ((row & 7) << 4));
        af[t] = *reinterpret_cast<const bf16x8*>(reinterpret_cast<const char*>(sa) + aoff);
        const int col = wc + t * 16 + lo16;
        const int boff = col * 128 + (inner ^ ((col & 7) << 4));
        bf1[t] = *reinterpret_cast<const bf16x8*>(reinterpret_cast<const char*>(sb1) + boff);
        bf2[t] = *reinterpret_cast<const bf16x8*>(reinterpret_cast<const char*>(sb2) + boff);
      }
#pragma unroll
      for (int rt = 0; rt < 4; ++rt)
#pragma unroll
        for (int ct = 0; ct < 4; ++ct) {
          au[rt][ct] = __builtin_amdgcn_mfma_f32_16x16x32_bf16(af[rt], bf1[ct], au[rt][ct], 0, 0, 0);
          av[rt][ct] = __builtin_amdgcn_mfma_f32_16x16x32_bf16(af[rt], bf2[ct], av[rt][ct], 0, 0, 0);
        }
    }
  }
#pragma unroll
  for (int ct = 0; ct < 4; ++ct) {
    const int colg = col0 + wc + ct * 16 + lo16;
    const float bv1 = b1[colg], bv2 = b2[colg];
#pragma unroll
    for (int rt = 0; rt < 4; ++rt) {
#pragma unroll
      for (int j = 0; j < 4; ++j) {
        const int r = row0 + wr + rt * 16 + hi * 4 + j;
        const float vh = au[rt][ct][j] + bv1;
        const float vt = av[rt][ct][j] + bv2;
        C1[(size_t)r * DH + colg] = vh;
        EHb[(size_t)r * DH + colg] = f2bf(vh * kscale);
        C2[(size_t)r * DH + colg] = vt;
        const size_t idx = (size_t)(r >> 4) * 8192 + (size_t)(colg >> 5) * 512 +
                           (size_t)((((colg & 31) >> 3) * 16 + (r & 15)) * 8) + (colg & 7);
        ETp[idx] = f2bf(vt);
      }
    }
  }
}

// ---------------------------------------------------------------------------
// Fused l1/l2 GEMM: emb = lrelu(U@l1+b1) + lrelu(V@l2+b2), bf16 out only.
// Dual A (Ub, Vb), dual W. No fp32 round-trip, no ACC pass.
// ---------------------------------------------------------------------------
__global__ __launch_bounds__(256) void gemm128_l1l2(
    const unsigned short* __restrict__ Ub, const unsigned short* __restrict__ Vb,
    const unsigned short* __restrict__ W1, const unsigned short* __restrict__ W2,
    const float* __restrict__ b1, const float* __restrict__ b2,
    unsigned short* __restrict__ EMBb) {
  __shared__ unsigned short sa1[128 * 64];
  __shared__ unsigned short sa2[128 * 64];
  __shared__ unsigned short sb1[128 * 64];
  __shared__ unsigned short sb2[128 * 64];
  const int tid = threadIdx.x;
  const int wave = tid >> 6, lane = tid & 63;
  const int lo16 = lane & 15, hi = lane >> 4;
  const int wr = (wave >> 1) << 6, wc = (wave & 1) << 6;
  const int row0 = blockIdx.y << 7, col0 = blockIdx.x << 7;
  f32x4 au[4][4], av[4][4];
#pragma unroll
  for (int rt = 0; rt < 4; ++rt)
#pragma unroll
    for (int ct = 0; ct < 4; ++ct) {
      au[rt][ct].x = 0.f; au[rt][ct].y = 0.f; au[rt][ct].z = 0.f; au[rt][ct].w = 0.f;
      av[rt][ct].x = 0.f; av[rt][ct].y = 0.f; av[rt][ct].z = 0.f; av[rt][ct].w = 0.f;
    }
  for (int k0 = 0; k0 < DH; k0 += 64) {
    __syncthreads();
#pragma unroll
    for (int i = 0; i < 4; ++i) {
      const int c = i * 256 + tid;
      const int r = c >> 3, i8 = c & 7;
      const int byte = r * 128 + ((i8 * 16) ^ ((r & 7) << 4));
      *reinterpret_cast<bf16x8*>(reinterpret_cast<char*>(sa1) + byte) =
          *reinterpret_cast<const bf16x8*>(Ub + (size_t)(row0 + r) * DH + k0 + i8 * 8);
      *reinterpret_cast<bf16x8*>(reinterpret_cast<char*>(sa2) + byte) =
          *reinterpret_cast<const bf16x8*>(Vb + (size_t)(row0 + r) * DH + k0 + i8 * 8);
      *reinterpret_cast<bf16x8*>(reinterpret_cast<char*>(sb1) + byte) =
          *reinterpret_cast<const bf16x8*>(W1 + (size_t)(col0 + r) * DH + k0 + i8 * 8);
      *reinterpret_cast<bf16x8*>(reinterpret_cast<char*>(sb2) + byte) =
          *reinterpret_cast<const bf16x8*>(W2 + (size_t)(col0 + r) * DH + k0 + i8 * 8);
    }
    __syncthreads();
#pragma unroll
    for (int kk2 = 0; kk2 < 2; ++kk2) {
      const int inner = (kk2 << 6) + (hi << 4);
      bf16x8 a1[4], a2[4], bf1[4], bf2[4];
#pragma unroll
      for (int t = 0; t < 4; ++t) {
        const int row = wr + t * 16 + lo16;
        const int aoff = row * 128 + (inner ^ ((row & 7) << 4));
        a1[t] = *reinterpret_cast<const bf16x8*>(reinterpret_cast<const char*>(sa1) + aoff);
        a2[t] = *reinterpret_cast<const bf16x8*>(reinterpret_cast<const char*>(sa2) + aoff);
        const int col = wc + t * 16 + lo16;
        const int boff = col * 128 + (inner ^ ((col & 7) << 4));
        bf1[t] = *reinterpret_cast<const bf16x8*>(reinterpret_cast<const char*>(sb1) + boff);
        bf2[t] = *reinterpret_cast<const bf16x8*>(reinterpret_cast<const char*>(sb2) + boff);
      }
#pragma unroll
      for (int rt = 0; rt < 4; ++rt)
#pragma unroll
        for (int ct = 0; ct < 4; ++ct) {
          au[rt][ct] = __builtin_amdgcn_mfma_f32_16x16x32_bf16(a1[rt], bf1[ct], au[rt][ct], 0, 0, 0);
          av[rt][ct] = __builtin_amdgcn_mfma_f32_16x16x32_bf16(a2[rt], bf2[ct], av[rt][ct], 0, 0, 0);
        }
    }
  }
#pragma unroll
  for (int ct = 0; ct < 4; ++ct) {
    const int colg = col0 + wc + ct * 16 + lo16;
    const float bv1 = b1[colg], bv2 = b2[colg];
#pragma unroll
    for (int rt = 0; rt < 4; ++rt) {
#pragma unroll
      for (int j = 0; j < 4; ++j) {
        const int r = row0 + wr + rt * 16 + hi * 4 + j;
        float u = au[rt][ct][j] + bv1;
        float v = av[rt][ct][j] + bv2;
        u = u > 0.f ? u : NEG_SLOPE * u;
        v = v > 0.f ? v : NEG_SLOPE * v;
        EMBb[(size_t)r * DH + colg] = f2bf(u + v);
      }
    }
  }
}

// ---------------------------------------------------------------------------
// Column sums of X[8192 x 512]
// ---------------------------------------------------------------------------
__global__ __launch_bounds__(256) void colsum_kernel(const float* __restrict__ X,
                                                     float* __restrict__ cs) {
  const int tid = threadIdx.x;
  float s0 = 0.f, s1 = 0.f;
  const int r0 = blockIdx.x * 128;
  for (int r = r0; r < r0 + 128; ++r) {
    s0 += X[(size_t)r * DH + tid];
    s1 += X[(size_t)r * DH + tid + 256];
  }
  atomicAdd(&cs[tid], s0);
  atomicAdd(&cs[tid + 256], s1);
}

// x = (x + colmean) * 0.5 ; emit bf16 copy only (fp32 x is dead afterwards)
__global__ __launch_bounds__(256) void mix_kernel(float* __restrict__ X,
                                                  const float* __restrict__ cs,
                                                  unsigned short* __restrict__ Xb) {
  const size_t gid = (size_t)blockIdx.x * 256 + threadIdx.x;
  const int c4 = ((int)gid & 127) << 2;
  float4 x = *reinterpret_cast<float4*>(X + gid * 4);
  const float inv = 1.f / 8192.f;
  x.x = (x.x + cs[c4 + 0] * inv) * 0.5f;
  x.y = (x.y + cs[c4 + 1] * inv) * 0.5f;
  x.z = (x.z + cs[c4 + 2] * inv) * 0.5f;
  x.w = (x.w + cs[c4 + 3] * inv) * 0.5f;
  ushort4 o;
  o.x = f2bf(x.x); o.y = f2bf(x.y); o.z = f2bf(x.z); o.w = f2bf(x.w);
  *reinterpret_cast<ushort4*>(Xb + gid * 4) = o;
}

// ---------------------------------------------------------------------------
// MFMA scoring + streaming top-6 (r6-proven version: coalesced packed-B,
// 1-deep B prefetch, no A register double-buffer).
// ---------------------------------------------------------------------------
__global__ __launch_bounds__(512, 2) void score_topk_v3(
    const unsigned short* __restrict__ EHb, const unsigned short* __restrict__ ETp,
    float* __restrict__ tkv, int* __restrict__ tki) {
  __shared__ unsigned short sa[128 * 512];  // 131072 B, swizzled A
  __shared__ float swb[8][8 * 68];          // 17408 B, per-wave score slices
  const int tid = threadIdx.x;
  const int wave = tid >> 6, lane = tid & 63;
  const int lo16 = lane & 15, hi = lane >> 4;
  const int bid = blockIdx.x;
  const int split = (bid & 7) >> 1;
  const int rowblk = ((bid >> 3) << 1) | (bid & 1);
  const int grow0 = rowblk << 7;       // 128 rows/block
  const int colbase0 = split << 11;    // 2048 cols/split

#pragma unroll
  for (int i = 0; i < 16; ++i) {
    const int c = i * 512 + tid;
    const int row = c >> 6, i8 = c & 63;
    const bf16x8 v = *reinterpret_cast<const bf16x8*>(
        EHb + (size_t)(grow0 + row) * DH + i8 * 8);
    const int byte = row * 1024 + ((i8 * 16) ^ ((row & 7) << 4));
    *reinterpret_cast<bf16x8*>(reinterpret_cast<char*>(sa) + byte) = v;
  }
  __syncthreads();

  float tv[2][6];
  int ti[2][6];
#pragma unroll
  for (int a = 0; a < 2; ++a)
#pragma unroll
    for (int s = 0; s < 6; ++s) { tv[a][s] = -3.4e38f; ti[a][s] = 0; }

  float* sw = swb[wave];

  bf16x8 bcur[4];
  {
    const int jg0 = (colbase0 + wave * 64) >> 4;
#pragma unroll
    for (int ct = 0; ct < 4; ++ct)
      bcur[ct] = *reinterpret_cast<const bf16x8*>(
          ETp + (size_t)(jg0 + ct) * 8192 + lane * 8);
  }

  for (int jt = 0; jt < 4; ++jt) {
    const int wcol0 = colbase0 + jt * 512 + wave * 64;
    const int jgbase = wcol0 >> 4;
    f32x4 acc[8][4];
#pragma unroll
    for (int rt = 0; rt < 8; ++rt)
#pragma unroll
      for (int ct = 0; ct < 4; ++ct) {
        acc[rt][ct].x = 0.f; acc[rt][ct].y = 0.f; acc[rt][ct].z = 0.f; acc[rt][ct].w = 0.f;
      }
#pragma unroll
    for (int kk = 0; kk < 16; ++kk) {
      bf16x8 bnxt[4];
      if (kk < 15) {
#pragma unroll
        for (int ct = 0; ct < 4; ++ct)
          bnxt[ct] = *reinterpret_cast<const bf16x8*>(
              ETp + (size_t)(jgbase + ct) * 8192 + (kk + 1) * 512 + lane * 8);
      } else {
        const int jtn = (jt == 3) ? 3 : (jt + 1);
        const int jgn = (colbase0 + jtn * 512 + wave * 64) >> 4;
#pragma unroll
        for (int ct = 0; ct < 4; ++ct)
          bnxt[ct] = *reinterpret_cast<const bf16x8*>(
              ETp + (size_t)(jgn + ct) * 8192 + lane * 8);
      }
      const int inner = (kk << 6) + (hi << 4);
#pragma unroll
      for (int rt = 0; rt < 8; ++rt) {
        const int row = rt * 16 + lo16;
        const bf16x8 af = *reinterpret_cast<const bf16x8*>(
            reinterpret_cast<const char*>(sa) + row * 1024 + (inner ^ ((row & 7) << 4)));
#pragma unroll
        for (int ct = 0; ct < 4; ++ct)
          acc[rt][ct] = __builtin_amdgcn_mfma_f32_16x16x32_bf16(af, bcur[ct], acc[rt][ct], 0, 0, 0);
      }
#pragma unroll
      for (int ct = 0; ct < 4; ++ct) bcur[ct] = bnxt[ct];
    }
#pragma unroll
    for (int a = 0; a < 2; ++a) {
#pragma unroll
      for (int ct = 0; ct < 4; ++ct) {
#pragma unroll
        for (int h = 0; h < 2; ++h) {
          if ((lo16 >> 3) == h) {
#pragma unroll
            for (int rtl = 0; rtl < 4; ++rtl)
              *reinterpret_cast<f32x4*>(sw + (lo16 & 7) * 68 + rtl * 16 + hi * 4) =
                  acc[a * 4 + rtl][ct];
          }
          asm volatile("s_waitcnt lgkmcnt(0)" ::: "memory");
#pragma unroll
          for (int cc = 0; cc < 8; ++cc) {
            const float v = sw[cc * 68 + lane];
            const int col = wcol0 + ct * 16 + h * 8 + cc;
            if (v > tv[a][5]) {
              tv[a][5] = v; ti[a][5] = col;
#pragma unroll
              for (int p = 5; p > 0; --p) {
                if (tv[a][p] > tv[a][p - 1]) {
                  float tvt = tv[a][p]; tv[a][p] = tv[a][p - 1]; tv[a][p - 1] = tvt;
                  int tit = ti[a][p]; ti[a][p] = ti[a][p - 1]; ti[a][p - 1] = tit;
                }
              }
            }
          }
          asm volatile("s_waitcnt lgkmcnt(0)" ::: "memory");
        }
      }
    }
  }
  __syncthreads();
  float* mv = reinterpret_cast<float*>(sa);
  int* mi = reinterpret_cast<int*>(mv + 128 * 8 * 6);
#pragma unroll
  for (int a = 0; a < 2; ++a) {
    const int row = a * 64 + lane;
#pragma unroll
    for (int s = 0; s < 6; ++s) {
      mv[(row * 8 + wave) * 6 + s] = tv[a][s];
      mi[(row * 8 + wave) * 6 + s] = ti[a][s];
    }
  }
  __syncthreads();
  if (tid < 128) {
    int pq[8] = {0, 0, 0, 0, 0, 0, 0, 0};
    const int base = (split * N_NODES + grow0 + tid) * 6;
    for (int s = 0; s < 6; ++s) {
      float best = -3.4e38f;
      int bi = 0x7fffffff, bq = 0;
#pragma unroll
      for (int q = 0; q < 8; ++q) {
        if (pq[q] < 6) {
          const float v = mv[(tid * 8 + q) * 6 + pq[q]];
          const int ix = mi[(tid * 8 + q) * 6 + pq[q]];
          if (v > best || (v == best && ix < bi)) { best = v; bi = ix; bq = q; }
        }
      }
      tkv[base + s] = best;
      tki[base + s] = bi;
#pragma unroll
      for (int q = 0; q < 8; ++q) pq[q] += (bq == q) ? 1 : 0;
    }
  }
}

// merge the 4 j-split top-6 lists into final top-6
__global__ __launch_bounds__(256) void merge_topk4(const float* __restrict__ tkv,
                                                   const int* __restrict__ tki,
                                                   float* __restrict__ fw,
                                                   int* __restrict__ fi) {
  const int n = blockIdx.x * 256 + threadIdx.x;
  int pq[NSPLIT] = {0, 0, 0, 0};
  for (int s = 0; s < 6; ++s) {
    float best = -3.4e38f;
    int bi = 0x7fffffff, bq = 0;
#pragma unroll
    for (int q = 0; q < NSPLIT; ++q) {
      if (pq[q] < 6) {
        const float v = tkv[((size_t)q * N_NODES + n) * 6 + pq[q]];
        const int ix = tki[((size_t)q * N_NODES + n) * 6 + pq[q]];
        if (v > best || (v == best && ix < bi)) { best = v; bi = ix; bq = q; }
      }
    }
    fw[n * 6 + s] = best;
    fi[n * 6 + s] = bi;
#pragma unroll
    for (int q = 0; q < NSPLIT; ++q) pq[q] += (bq == q) ? 1 : 0;
  }
}

// ---------------------------------------------------------------------------
// Per-node neighbor aggregation; outputs Ub, Vb in bf16.
// ---------------------------------------------------------------------------
__global__ __launch_bounds__(256) void agg_kernel(const float* __restrict__ EH,
                                                  const float* __restrict__ ET,
                                                  const float* __restrict__ fw,
                                                  const int* __restrict__ fi,
                                                  unsigned short* __restrict__ Ub,
                                                  unsigned short* __restrict__ Vb) {
  __shared__ float sNb[KNB][DH];
  __shared__ float sred[4][8];
  __shared__ float ska[8];
  const int node = blockIdx.x;
  const int tid = threadIdx.x;
  float w[KNB];
  int idx[KNB];
#pragma unroll
  for (int k = 0; k < KNB; ++k) {
    w[k] = fw[node * KNB + k];
    idx[k] = fi[node * KNB + k];
  }
  float mx = w[0];
#pragma unroll
  for (int k = 1; k < KNB; ++k) mx = fmaxf(mx, w[k]);
  float pk[KNB];
  float se = 0.f;
#pragma unroll
  for (int k = 0; k < KNB; ++k) { pk[k] = expf(w[k] - mx); se += pk[k]; }
  const float inv_se = 1.f / se;
#pragma unroll
  for (int k = 0; k < KNB; ++k) pk[k] *= inv_se;
  for (int e = tid; e < KNB * DH; e += 256) {
    int k = e >> 9, d = e & 511;
    sNb[k][d] = ET[(size_t)idx[k] * DH + d];
  }
  __syncthreads();
  float eh[2];
  eh[0] = EH[(size_t)node * DH + tid];
  eh[1] = EH[(size_t)node * DH + tid + 256];
  float ka[KNB] = {0, 0, 0, 0, 0, 0};
#pragma unroll
  for (int t = 0; t < 2; ++t) {
    const int d = tid + t * 256;
    const float e_ = eh[t];
#pragma unroll
    for (int k = 0; k < KNB; ++k) {
      float Nb = sNb[k][d];
      float ehr = pk[k] * Nb + (1.f - pk[k]) * e_;
      float g = tanhf(e_ + ehr);
      ka[k] = fmaf(Nb, g, ka[k]);
    }
  }
#pragma unroll
  for (int k = 0; k < KNB; ++k) {
    float v = ka[k];
#pragma unroll
    for (int off = 32; off > 0; off >>= 1) v += __shfl_down(v, off, 64);
    if ((tid & 63) == 0) sred[tid >> 6][k] = v;
  }
  __syncthreads();
  if (tid < KNB) ska[tid] = sred[0][tid] + sred[1][tid] + sred[2][tid] + sred[3][tid];
  __syncthreads();
  float kav[KNB];
#pragma unroll
  for (int k = 0; k < KNB; ++k) kav[k] = ska[k];
  float kmx = kav[0];
#pragma unroll
  for (int k = 1; k < KNB; ++k) kmx = fmaxf(kmx, kav[k]);
  float kp[KNB];
  float ks = 0.f;
#pragma unroll
  for (int k = 0; k < KNB; ++k) { kp[k] = expf(kav[k] - kmx); ks += kp[k]; }
  const float inv_ks = 1.f / ks;
#pragma unroll
  for (int k = 0; k < KNB; ++k) kp[k] *= inv_ks;
#pragma unroll
  for (int t = 0; t < 2; ++t) {
    const int d = tid + t * 256;
    float eNh = 0.f;
#pragma unroll
    for (int k = 0; k < KNB; ++k) eNh = fmaf(kp[k], sNb[k][d], eNh);
    const float e_ = eh[t];
    Ub[(size_t)node * DH + d] = f2bf(e_ + eNh);
    Vb[(size_t)node * DH + d] = f2bf(e_ * eNh);
  }
}

// a[n] = dot(hid_bf16[n], att2_w) + att2_b ; one wave per node
__global__ __launch_bounds__(256) void att_dot(const unsigned short* __restrict__ HIDb,
                                               const float* __restrict__ w2,
                                               const float* __restrict__ b2,
                                               float* __restrict__ a) {
  const int wid = threadIdx.x >> 6, lane = threadIdx.x & 63;
  const int node = blockIdx.x * 4 + wid;
  const ushort4 h4 = *reinterpret_cast<const ushort4*>(HIDb + (size_t)node * 256 + lane * 4);
  const float4 w4 = *reinterpret_cast<const float4*>(w2 + lane * 4);
  float s = bf2f(h4.x) * w4.x + bf2f(h4.y) * w4.y + bf2f(h4.z) * w4.z + bf2f(h4.w) * w4.w;
#pragma unroll
  for (int off = 32; off > 0; off >>= 1) s += __shfl_down(s, off, 64);
  if (lane == 0) a[node] = s + b2[0];
}

// global softmax stats over a[8192]
__global__ __launch_bounds__(1024) void softmax_stats(const float* __restrict__ a,
                                                      float* __restrict__ st) {
  __shared__ float red[16];
  __shared__ float bc;
  const int tid = threadIdx.x;
  float mx = -3.4e38f;
  for (int i = tid; i < N_NODES; i += 1024) mx = fmaxf(mx, a[i]);
#pragma unroll
  for (int off = 32; off > 0; off >>= 1) mx = fmaxf(mx, __shfl_xor(mx, off, 64));
  if ((tid & 63) == 0) red[tid >> 6] = mx;
  __syncthreads();
  if (tid == 0) {
    float m = red[0];
    for (int i = 1; i < 16; ++i) m = fmaxf(m, red[i]);
    bc = m;
  }
  __syncthreads();
  const float gm = bc;
  float se = 0.f;
  for (int i = tid; i < N_NODES; i += 1024) se += expf(a[i] - gm);
#pragma unroll
  for (int off = 32; off > 0; off >>= 1) se += __shfl_xor(se, off, 64);
  if ((tid & 63) == 0) red[tid >> 6] = se;
  __syncthreads();
  if (tid == 0) {
    float s = 0.f;
    for (int i = 0; i < 16; ++i) s += red[i];
    st[0] = gm;
    st[1] = s;
  }
}

// h[c] = sum_n softmax(a)_n * emb_bf16[n][c]
__global__ __launch_bounds__(256) void readout(const unsigned short* __restrict__ EMBb,
                                               const float* __restrict__ a,
                                               const float* __restrict__ st,
                                               float* __restrict__ h) {
  __shared__ float sacc[4][64];
  const int tid = threadIdx.x;
  const int c = (blockIdx.x << 6) + (tid & 63);
  const int rsub = tid >> 6;
  const float mx = st[0], inv_se = 1.f / st[1];
  const int r0 = blockIdx.y << 8;
  float acc = 0.f;
  for (int i = 0; i < 64; ++i) {
    const int r = r0 + (i << 2) + rsub;
    const float g = expf(a[r] - mx);
    acc = fmaf(g, bf2f(EMBb[(size_t)r * DH + c]), acc);
  }
  sacc[rsub][tid & 63] = acc * inv_se;
  __syncthreads();
  if (rsub == 0) {
    float t = sacc[0][tid] + sacc[1][tid] + sacc[2][tid] + sacc[3][tid];
    atomicAdd(&h[c], t);
  }
}

// layernorm + final fc -> 2 logits
__global__ __launch_bounds__(512) void finalize(const float* __restrict__ h,
                                                const float* __restrict__ ln_g,
                                                const float* __restrict__ ln_b,
                                                const float* __restrict__ fc_w,
                                                const float* __restrict__ fc_b,
                                                float* __restrict__ out) {
  __shared__ float red0[8];
  __shared__ float red1[8];
  __shared__ float bc[2];
  const int tid = threadIdx.x;
  const int wid = tid >> 6, lane = tid & 63;
  const float v = h[tid];
  float s = v;
#pragma unroll
  for (int off = 32; off > 0; off >>= 1) s += __shfl_xor(s, off, 64);
  if (lane == 0) red0[wid] = s;
  __syncthreads();
  if (tid == 0) {
    float t = 0.f;
    for (int i = 0; i < 8; ++i) t += red0[i];
    bc[0] = t * (1.f / 512.f);
  }
  __syncthreads();
  const float mu = bc[0];
  const float dv = v - mu;
  s = dv * dv;
#pragma unroll
  for (int off = 32; off > 0; off >>= 1) s += __shfl_xor(s, off, 64);
  if (lane == 0) red0[wid] = s;
  __syncthreads();
  if (tid == 0) {
    float t = 0.f;
    for (int i = 0; i < 8; ++i) t += red0[i];
    bc[1] = t * (1.f / 512.f);
  }
  __syncthreads();
  const float var = bc[1];
  const float hn = dv / sqrtf(var + 1e-5f) * ln_g[tid] + ln_b[tid];
  float l0 = hn * fc_w[tid * 2 + 0];
  float l1 = hn * fc_w[tid * 2 + 1];
#pragma unroll
  for (int off = 32; off > 0; off >>= 1) {
    l0 += __shfl_xor(l0, off, 64);
    l1 += __shfl_xor(l1, off, 64);
  }
  if (lane == 0) { red0[wid] = l0; red1[wid] = l1; }
  __syncthreads();
  if (tid == 0) {
    float t0 = 0.f, t1 = 0.f;
    for (int i = 0; i < 8; ++i) { t0 += red0[i]; t1 += red1[i]; }
    out[0] = t0 + fc_b[0];
    out[1] = t1 + fc_b[1];
  }
}

// ---------------------------------------------------------------------------
extern "C" void kernel_launch(void* const* d_in, const int* in_sizes, int n_in,
                              void* d_out, int out_size, void* d_ws, size_t ws_size,
                              hipStream_t stream) {
  const float* x_s    = (const float*)d_in[0];
  const float* fc1_w  = (const float*)d_in[1];
  const float* fc1_b  = (const float*)d_in[2];
  const float* wh_w   = (const float*)d_in[3];
  const float* wh_b   = (const float*)d_in[4];
  const float* wt_w   = (const float*)d_in[5];
  const float* wt_b   = (const float*)d_in[6];
  const float* l1_w   = (const float*)d_in[7];
  const float* l1_b   = (const float*)d_in[8];
  const float* l2_w   = (const float*)d_in[9];
  const float* l2_b   = (const float*)d_in[10];
  const float* att1_w = (const float*)d_in[11];
  const float* att1_b = (const float*)d_in[12];
  const float* att2_w = (const float*)d_in[13];
  const float* att2_b = (const float*)d_in[14];
  const float* ln_g   = (const float*)d_in[15];
  const float* ln_b   = (const float*)d_in[16];
  const float* fc_w   = (const float*)d_in[17];
  const float* fc_b   = (const float*)d_in[18];

  float* ws = (float*)d_ws;
  const size_t BIG = (size_t)N_NODES * DH;  // 4,194,304
  float* B1 = ws;                                        // x fp32 -> e_h fp32
  float* B2 = ws + BIG;                                  // e_t fp32
  unsigned short* R1 = (unsigned short*)(ws + 2 * BIG);  // xsb -> EHb -> Ub -> hidb
  unsigned short* R2 = R1 + BIG;                          // xb -> Vb
  unsigned short* R3 = R2 + BIG;                          // ETp (packed) -> embb
  unsigned short* WT = R3 + BIG;                          // transposed bf16 weights
  float* tail = (float*)(WT + 1376256);
  float* tkv    = tail;                          // 4*8192*6
  int*   tki    = (int*)(tkv + NSPLIT * N_NODES * 6);
  float* fwv    = (float*)(tki + NSPLIT * N_NODES * 6);
  int*   fiv    = (int*)(fwv + N_NODES * 6);
  float* colsum = (float*)(fiv + N_NODES * 6);
  float* av     = colsum + DH;
  float* stats  = av + N_NODES;
  float* hbuf   = stats + 16;

  unsigned short* fc1t  = WT + 0;
  unsigned short* wht   = WT + 196608;
  unsigned short* wtt   = WT + 458752;
  unsigned short* l1t   = WT + 720896;
  unsigned short* l2t   = WT + 983040;
  unsigned short* att1t = WT + 1245184;

  const float kscale = 0.044194173824159216f;  // 512^-0.5

  // 0. prep
  prep_weights<<<5376, 256, 0, stream>>>(fc1_w, wh_w, wt_w, l1_w, l2_w, att1_w, WT);
  convert_xs<<<3072, 256, 0, stream>>>(x_s, R1);
  // 1. x = lrelu(xsb @ fc1t^T + b) -> B1 fp32
  gemm128<1, 1, 0><<<dim3(4, 64), 256, 0, stream>>>(
      R1, fc1t, fc1_b, B1, nullptr, DIN, DH);
  // 2. mean-mix -> xb bf16 (R2)
  hipMemsetAsync(colsum, 0, DH * sizeof(float), stream);
  colsum_kernel<<<64, 256, 0, stream>>>(B1, colsum);
  mix_kernel<<<4096, 256, 0, stream>>>(B1, colsum, R2);
  // 3. fused e_h/e_t: e_h -> B1 fp32 + EHb*kscale (R1); e_t -> B2 fp32 + ETp (R3)
  gemm128_ehet<<<dim3(4, 64), 256, 0, stream>>>(
      R2, wht, wtt, wh_b, wt_b, B1, R1, B2, R3, kscale);
  // 4. scoring (r6-proven) + merge
  score_topk_v3<<<256, 512, 0, stream>>>(R1, R3, tkv, tki);
  merge_topk4<<<32, 256, 0, stream>>>(tkv, tki, fwv, fiv);
  // 5. aggregation -> Ub (R1), Vb (R2)
  agg_kernel<<<N_NODES, 256, 0, stream>>>(B1, B2, fwv, fiv, R1, R2);
  // 6. fused l1/l2 -> embb (R3), no fp32 round-trip
  gemm128_l1l2<<<dim3(4, 64), 256, 0, stream>>>(
      R1, R2, l1t, l2t, l1_b, l2_b, R3);
  // 7. attention readout: hid = lrelu(embb@att1+b) -> hidb (R1)
  gemm128<1, 0, 1><<<dim3(2, 64), 256, 0, stream>>>(
      R3, att1t, att1_b, nullptr, R1, DH, 256);
  att_dot<<<2048, 256, 0, stream>>>(R1, att2_w, att2_b, av);
  softmax_stats<<<1, 1024, 0, stream>>>(av, stats);
  hipMemsetAsync(hbuf, 0, DH * sizeof(float), stream);
  readout<<<dim3(8, 32), 256, 0, stream>>>(R3, av, stats, hbuf);
  // 8. layernorm + logits
  finalize<<<1, 512, 0, stream>>>(hbuf, ln_g, ln_b, fc_w, fc_b, (float*)d_out);
}

// Round 9
// 357.120 us; speedup vs baseline: 1.2087x; 1.1382x over previous
//
#include <hip/hip_runtime.h>
#include <hip/hip_bf16.h>
#include <math.h>

#define N_NODES 8192
#define DIN 384
#define DH 512
#define KNB 6
#define NEG_SLOPE 0.01f
#define NSPLIT 4

typedef __attribute__((ext_vector_type(8))) short bf16x8;
typedef __attribute__((ext_vector_type(4))) float f32x4;

__device__ __forceinline__ unsigned short f2bf(float x) {
  unsigned int u = __float_as_uint(x);
  unsigned int r = (u + 0x7fffu + ((u >> 16) & 1u)) >> 16;  // RNE
  return (unsigned short)r;
}
__device__ __forceinline__ float bf2f(unsigned short u) {
  return __uint_as_float(((unsigned int)u) << 16);
}

// ---------------------------------------------------------------------------
// Weight prep: W[K][N] fp32 -> Wt[N][K] bf16, all 6 weights into one pool.
// ---------------------------------------------------------------------------
__global__ __launch_bounds__(256) void prep_weights(
    const float* __restrict__ w0, const float* __restrict__ w1,
    const float* __restrict__ w2, const float* __restrict__ w3,
    const float* __restrict__ w4, const float* __restrict__ w5,
    unsigned short* __restrict__ pool) {
  const int f = blockIdx.x * 256 + threadIdx.x;
  const int E0 = 196608, E1 = 458752, E2 = 720896, E3 = 983040, E4 = 1245184, E5 = 1376256;
  if (f >= E5) return;
  const float* src; int off, Kw, Nw;
  if (f < E0)      { src = w0; off = 0;  Kw = 384; Nw = 512; }
  else if (f < E1) { src = w1; off = E0; Kw = 512; Nw = 512; }
  else if (f < E2) { src = w2; off = E1; Kw = 512; Nw = 512; }
  else if (f < E3) { src = w3; off = E2; Kw = 512; Nw = 512; }
  else if (f < E4) { src = w4; off = E3; Kw = 512; Nw = 512; }
  else             { src = w5; off = E4; Kw = 512; Nw = 256; }
  const int local = f - off;
  const int n = local / Kw, k = local - n * Kw;
  pool[f] = f2bf(src[(size_t)k * Nw + n]);
}

// x_s fp32 -> bf16
__global__ __launch_bounds__(256) void convert_xs(const float* __restrict__ xs,
                                                  unsigned short* __restrict__ out) {
  const size_t i = ((size_t)blockIdx.x * 256 + threadIdx.x) * 4;
  const float4 v = *reinterpret_cast<const float4*>(xs + i);
  ushort4 o;
  o.x = f2bf(v.x); o.y = f2bf(v.y); o.z = f2bf(v.z); o.w = f2bf(v.w);
  *reinterpret_cast<ushort4*>(out + i) = o;
}

// ---------------------------------------------------------------------------
// 128x128-tile bf16 MFMA GEMM (single A, single W). 4 waves, each owns a
// 64x64 quadrant: per 32-k step 8 ds_read_b128 -> 16 MFMAs.
// ---------------------------------------------------------------------------
template <int ACT, int WF32, int WBF16>
__global__ __launch_bounds__(256) void gemm128(
    const unsigned short* __restrict__ A, const unsigned short* __restrict__ Wt,
    const float* __restrict__ bias, float* __restrict__ C,
    unsigned short* __restrict__ Cb, int K, int N) {
  __shared__ unsigned short sa[128 * 64];
  __shared__ unsigned short sb[128 * 64];
  const int tid = threadIdx.x;
  const int wave = tid >> 6, lane = tid & 63;
  const int lo16 = lane & 15, hi = lane >> 4;
  const int wr = (wave >> 1) << 6, wc = (wave & 1) << 6;
  const int row0 = blockIdx.y << 7, col0 = blockIdx.x << 7;
  f32x4 acc[4][4];
#pragma unroll
  for (int rt = 0; rt < 4; ++rt)
#pragma unroll
    for (int ct = 0; ct < 4; ++ct) { acc[rt][ct].x = 0.f; acc[rt][ct].y = 0.f; acc[rt][ct].z = 0.f; acc[rt][ct].w = 0.f; }
  for (int k0 = 0; k0 < K; k0 += 64) {
    __syncthreads();
#pragma unroll
    for (int i = 0; i < 4; ++i) {
      const int c = i * 256 + tid;  // 0..1023
      const int r = c >> 3, i8 = c & 7;
      const bf16x8 va = *reinterpret_cast<const bf16x8*>(A + (size_t)(row0 + r) * K + k0 + i8 * 8);
      const bf16x8 vb = *reinterpret_cast<const bf16x8*>(Wt + (size_t)(col0 + r) * K + k0 + i8 * 8);
      const int byte = r * 128 + ((i8 * 16) ^ ((r & 7) << 4));
      *reinterpret_cast<bf16x8*>(reinterpret_cast<char*>(sa) + byte) = va;
      *reinterpret_cast<bf16x8*>(reinterpret_cast<char*>(sb) + byte) = vb;
    }
    __syncthreads();
#pragma unroll
    for (int kk2 = 0; kk2 < 2; ++kk2) {
      const int inner = (kk2 << 6) + (hi << 4);
      bf16x8 af[4], bf[4];
#pragma unroll
      for (int t = 0; t < 4; ++t) {
        const int row = wr + t * 16 + lo16;
        af[t] = *reinterpret_cast<const bf16x8*>(reinterpret_cast<const char*>(sa) + row * 128 + (inner ^ ((row & 7) << 4)));
        const int col = wc + t * 16 + lo16;
        bf[t] = *reinterpret_cast<const bf16x8*>(reinterpret_cast<const char*>(sb) + col * 128 + (inner ^ ((col & 7) << 4)));
      }
#pragma unroll
      for (int rt = 0; rt < 4; ++rt)
#pragma unroll
        for (int ct = 0; ct < 4; ++ct)
          acc[rt][ct] = __builtin_amdgcn_mfma_f32_16x16x32_bf16(af[rt], bf[ct], acc[rt][ct], 0, 0, 0);
    }
  }
#pragma unroll
  for (int ct = 0; ct < 4; ++ct) {
    const int colg = col0 + wc + ct * 16 + lo16;
    const float bv = bias[colg];
#pragma unroll
    for (int rt = 0; rt < 4; ++rt) {
#pragma unroll
      for (int j = 0; j < 4; ++j) {
        const int r = row0 + wr + rt * 16 + hi * 4 + j;
        float v = acc[rt][ct][j] + bv;
        if (ACT) v = v > 0.f ? v : NEG_SLOPE * v;
        if (WF32) C[(size_t)r * N + colg] = v;
        if (WBF16) Cb[(size_t)r * N + colg] = f2bf(v);
      }
    }
  }
}

// ---------------------------------------------------------------------------
// Fused e_h/e_t GEMM: same A (xb), two weight tiles.
// ---------------------------------------------------------------------------
__global__ __launch_bounds__(256) void gemm128_ehet(
    const unsigned short* __restrict__ A,
    const unsigned short* __restrict__ W1, const unsigned short* __restrict__ W2,
    const float* __restrict__ b1, const float* __restrict__ b2,
    float* __restrict__ C1, unsigned short* __restrict__ EHb,
    float* __restrict__ C2, unsigned short* __restrict__ ETp, float kscale) {
  __shared__ unsigned short sa[128 * 64];
  __shared__ unsigned short sb1[128 * 64];
  __shared__ unsigned short sb2[128 * 64];
  const int tid = threadIdx.x;
  const int wave = tid >> 6, lane = tid & 63;
  const int lo16 = lane & 15, hi = lane >> 4;
  const int wr = (wave >> 1) << 6, wc = (wave & 1) << 6;
  const int row0 = blockIdx.y << 7, col0 = blockIdx.x << 7;
  f32x4 au[4][4], av[4][4];
#pragma unroll
  for (int rt = 0; rt < 4; ++rt)
#pragma unroll
    for (int ct = 0; ct < 4; ++ct) {
      au[rt][ct].x = 0.f; au[rt][ct].y = 0.f; au[rt][ct].z = 0.f; au[rt][ct].w = 0.f;
      av[rt][ct].x = 0.f; av[rt][ct].y = 0.f; av[rt][ct].z = 0.f; av[rt][ct].w = 0.f;
    }
  for (int k0 = 0; k0 < DH; k0 += 64) {
    __syncthreads();
#pragma unroll
    for (int i = 0; i < 4; ++i) {
      const int c = i * 256 + tid;
      const int r = c >> 3, i8 = c & 7;
      const int byte = r * 128 + ((i8 * 16) ^ ((r & 7) << 4));
      *reinterpret_cast<bf16x8*>(reinterpret_cast<char*>(sa) + byte) =
          *reinterpret_cast<const bf16x8*>(A + (size_t)(row0 + r) * DH + k0 + i8 * 8);
      *reinterpret_cast<bf16x8*>(reinterpret_cast<char*>(sb1) + byte) =
          *reinterpret_cast<const bf16x8*>(W1 + (size_t)(col0 + r) * DH + k0 + i8 * 8);
      *reinterpret_cast<bf16x8*>(reinterpret_cast<char*>(sb2) + byte) =
          *reinterpret_cast<const bf16x8*>(W2 + (size_t)(col0 + r) * DH + k0 + i8 * 8);
    }
    __syncthreads();
#pragma unroll
    for (int kk2 = 0; kk2 < 2; ++kk2) {
      const int inner = (kk2 << 6) + (hi << 4);
      bf16x8 af[4], bf1[4], bf2[4];
#pragma unroll
      for (int t = 0; t < 4; ++t) {
        const int row = wr + t * 16 + lo16;
        const int aoff = row * 128 + (inner ^ ((row & 7) << 4));
        af[t] = *reinterpret_cast<const bf16x8*>(reinterpret_cast<const char*>(sa) + aoff);
        const int col = wc + t * 16 + lo16;
        const int boff = col * 128 + (inner ^ ((col & 7) << 4));
        bf1[t] = *reinterpret_cast<const bf16x8*>(reinterpret_cast<const char*>(sb1) + boff);
        bf2[t] = *reinterpret_cast<const bf16x8*>(reinterpret_cast<const char*>(sb2) + boff);
      }
#pragma unroll
      for (int rt = 0; rt < 4; ++rt)
#pragma unroll
        for (int ct = 0; ct < 4; ++ct) {
          au[rt][ct] = __builtin_amdgcn_mfma_f32_16x16x32_bf16(af[rt], bf1[ct], au[rt][ct], 0, 0, 0);
          av[rt][ct] = __builtin_amdgcn_mfma_f32_16x16x32_bf16(af[rt], bf2[ct], av[rt][ct], 0, 0, 0);
        }
    }
  }
#pragma unroll
  for (int ct = 0; ct < 4; ++ct) {
    const int colg = col0 + wc + ct * 16 + lo16;
    const float bv1 = b1[colg], bv2 = b2[colg];
#pragma unroll
    for (int rt = 0; rt < 4; ++rt) {
#pragma unroll
      for (int j = 0; j < 4; ++j) {
        const int r = row0 + wr + rt * 16 + hi * 4 + j;
        const float vh = au[rt][ct][j] + bv1;
        const float vt = av[rt][ct][j] + bv2;
        C1[(size_t)r * DH + colg] = vh;
        EHb[(size_t)r * DH + colg] = f2bf(vh * kscale);
        C2[(size_t)r * DH + colg] = vt;
        const size_t idx = (size_t)(r >> 4) * 8192 + (size_t)(colg >> 5) * 512 +
                           (size_t)((((colg & 31) >> 3) * 16 + (r & 15)) * 8) + (colg & 7);
        ETp[idx] = f2bf(vt);
      }
    }
  }
}

// ---------------------------------------------------------------------------
// Fused l1/l2 GEMM: emb = lrelu(U@l1+b1) + lrelu(V@l2+b2), bf16 out only.
// ---------------------------------------------------------------------------
__global__ __launch_bounds__(256) void gemm128_l1l2(
    const unsigned short* __restrict__ Ub, const unsigned short* __restrict__ Vb,
    const unsigned short* __restrict__ W1, const unsigned short* __restrict__ W2,
    const float* __restrict__ b1, const float* __restrict__ b2,
    unsigned short* __restrict__ EMBb) {
  __shared__ unsigned short sa1[128 * 64];
  __shared__ unsigned short sa2[128 * 64];
  __shared__ unsigned short sb1[128 * 64];
  __shared__ unsigned short sb2[128 * 64];
  const int tid = threadIdx.x;
  const int wave = tid >> 6, lane = tid & 63;
  const int lo16 = lane & 15, hi = lane >> 4;
  const int wr = (wave >> 1) << 6, wc = (wave & 1) << 6;
  const int row0 = blockIdx.y << 7, col0 = blockIdx.x << 7;
  f32x4 au[4][4], av[4][4];
#pragma unroll
  for (int rt = 0; rt < 4; ++rt)
#pragma unroll
    for (int ct = 0; ct < 4; ++ct) {
      au[rt][ct].x = 0.f; au[rt][ct].y = 0.f; au[rt][ct].z = 0.f; au[rt][ct].w = 0.f;
      av[rt][ct].x = 0.f; av[rt][ct].y = 0.f; av[rt][ct].z = 0.f; av[rt][ct].w = 0.f;
    }
  for (int k0 = 0; k0 < DH; k0 += 64) {
    __syncthreads();
#pragma unroll
    for (int i = 0; i < 4; ++i) {
      const int c = i * 256 + tid;
      const int r = c >> 3, i8 = c & 7;
      const int byte = r * 128 + ((i8 * 16) ^ ((r & 7) << 4));
      *reinterpret_cast<bf16x8*>(reinterpret_cast<char*>(sa1) + byte) =
          *reinterpret_cast<const bf16x8*>(Ub + (size_t)(row0 + r) * DH + k0 + i8 * 8);
      *reinterpret_cast<bf16x8*>(reinterpret_cast<char*>(sa2) + byte) =
          *reinterpret_cast<const bf16x8*>(Vb + (size_t)(row0 + r) * DH + k0 + i8 * 8);
      *reinterpret_cast<bf16x8*>(reinterpret_cast<char*>(sb1) + byte) =
          *reinterpret_cast<const bf16x8*>(W1 + (size_t)(col0 + r) * DH + k0 + i8 * 8);
      *reinterpret_cast<bf16x8*>(reinterpret_cast<char*>(sb2) + byte) =
          *reinterpret_cast<const bf16x8*>(W2 + (size_t)(col0 + r) * DH + k0 + i8 * 8);
    }
    __syncthreads();
#pragma unroll
    for (int kk2 = 0; kk2 < 2; ++kk2) {
      const int inner = (kk2 << 6) + (hi << 4);
      bf16x8 a1[4], a2[4], bf1[4], bf2[4];
#pragma unroll
      for (int t = 0; t < 4; ++t) {
        const int row = wr + t * 16 + lo16;
        const int aoff = row * 128 + (inner ^ ((row & 7) << 4));
        a1[t] = *reinterpret_cast<const bf16x8*>(reinterpret_cast<const char*>(sa1) + aoff);
        a2[t] = *reinterpret_cast<const bf16x8*>(reinterpret_cast<const char*>(sa2) + aoff);
        const int col = wc + t * 16 + lo16;
        const int boff = col * 128 + (inner ^ ((col & 7) << 4));
        bf1[t] = *reinterpret_cast<const bf16x8*>(reinterpret_cast<const char*>(sb1) + boff);
        bf2[t] = *reinterpret_cast<const bf16x8*>(reinterpret_cast<const char*>(sb2) + boff);
      }
#pragma unroll
      for (int rt = 0; rt < 4; ++rt)
#pragma unroll
        for (int ct = 0; ct < 4; ++ct) {
          au[rt][ct] = __builtin_amdgcn_mfma_f32_16x16x32_bf16(a1[rt], bf1[ct], au[rt][ct], 0, 0, 0);
          av[rt][ct] = __builtin_amdgcn_mfma_f32_16x16x32_bf16(a2[rt], bf2[ct], av[rt][ct], 0, 0, 0);
        }
    }
  }
#pragma unroll
  for (int ct = 0; ct < 4; ++ct) {
    const int colg = col0 + wc + ct * 16 + lo16;
    const float bv1 = b1[colg], bv2 = b2[colg];
#pragma unroll
    for (int rt = 0; rt < 4; ++rt) {
#pragma unroll
      for (int j = 0; j < 4; ++j) {
        const int r = row0 + wr + rt * 16 + hi * 4 + j;
        float u = au[rt][ct][j] + bv1;
        float v = av[rt][ct][j] + bv2;
        u = u > 0.f ? u : NEG_SLOPE * u;
        v = v > 0.f ? v : NEG_SLOPE * v;
        EMBb[(size_t)r * DH + colg] = f2bf(u + v);
      }
    }
  }
}

// ---------------------------------------------------------------------------
// Column sums of X[8192 x 512]
// ---------------------------------------------------------------------------
__global__ __launch_bounds__(256) void colsum_kernel(const float* __restrict__ X,
                                                     float* __restrict__ cs) {
  const int tid = threadIdx.x;
  float s0 = 0.f, s1 = 0.f;
  const int r0 = blockIdx.x * 128;
  for (int r = r0; r < r0 + 128; ++r) {
    s0 += X[(size_t)r * DH + tid];
    s1 += X[(size_t)r * DH + tid + 256];
  }
  atomicAdd(&cs[tid], s0);
  atomicAdd(&cs[tid + 256], s1);
}

// x = (x + colmean) * 0.5 ; emit bf16 copy only
__global__ __launch_bounds__(256) void mix_kernel(float* __restrict__ X,
                                                  const float* __restrict__ cs,
                                                  unsigned short* __restrict__ Xb) {
  const size_t gid = (size_t)blockIdx.x * 256 + threadIdx.x;
  const int c4 = ((int)gid & 127) << 2;
  float4 x = *reinterpret_cast<float4*>(X + gid * 4);
  const float inv = 1.f / 8192.f;
  x.x = (x.x + cs[c4 + 0] * inv) * 0.5f;
  x.y = (x.y + cs[c4 + 1] * inv) * 0.5f;
  x.z = (x.z + cs[c4 + 2] * inv) * 0.5f;
  x.w = (x.w + cs[c4 + 3] * inv) * 0.5f;
  ushort4 o;
  o.x = f2bf(x.x); o.y = f2bf(x.y); o.z = f2bf(x.z); o.w = f2bf(x.w);
  *reinterpret_cast<ushort4*>(Xb + gid * 4) = o;
}

// ---------------------------------------------------------------------------
// MFMA scoring + streaming top-6, v6 ("occupancy"): R=32 rows/block, 4 waves,
// 1024 blocks (4 splits x 256 rowblocks) = 4 blocks/CU, 16 waves/CU.
// LDS 37.4 KB (32 KB swizzled A + 4.6 KB scan slices); regs capped at 128
// via __launch_bounds__(256,4) -> 4 waves/SIMD latency hiding (was 2).
// Packed-B coalesced loads (r6-proven), 1-deep prefetch.
// ---------------------------------------------------------------------------
__global__ __launch_bounds__(256, 4) void score_topk_v6(
    const unsigned short* __restrict__ EHb, const unsigned short* __restrict__ ETp,
    float* __restrict__ tkv, int* __restrict__ tki) {
  __shared__ unsigned short sa[32 * 512];  // 32768 B, swizzled A
  __shared__ float swb[4][8 * 36];         // 4608 B, per-wave score slices
  const int tid = threadIdx.x;
  const int wave = tid >> 6, lane = tid & 63;
  const int lo16 = lane & 15, hi = lane >> 4;
  const int bid = blockIdx.x;
  const int split = (bid & 7) >> 1;                 // XCD-pair owns a col strip
  const int rowblk = ((bid >> 3) << 1) | (bid & 1);
  const int grow0 = rowblk << 5;        // 32 rows/block
  const int colbase0 = split << 11;     // 2048 cols/split

  // stage A rows [grow0, grow0+32) swizzled: 2048 16B-chunks / 256 thr = 8
#pragma unroll
  for (int i = 0; i < 8; ++i) {
    const int c = i * 256 + tid;
    const int row = c >> 6, i8 = c & 63;
    const bf16x8 v = *reinterpret_cast<const bf16x8*>(
        EHb + (size_t)(grow0 + row) * DH + i8 * 8);
    const int byte = row * 1024 + ((i8 * 16) ^ ((row & 7) << 4));
    *reinterpret_cast<bf16x8*>(reinterpret_cast<char*>(sa) + byte) = v;
  }
  __syncthreads();

  float tv[6];
  int ti[6];
#pragma unroll
  for (int s = 0; s < 6; ++s) { tv[s] = -3.4e38f; ti[s] = 0; }

  float* sw = swb[wave];
  const int scanr = lane & 31, scang = lane >> 5;  // (row, col-group) partition

  // prologue: jt=0, kk=0 B-frags (coalesced packed)
  bf16x8 bcur[4];
  {
    const int jg0 = (colbase0 + wave * 64) >> 4;
#pragma unroll
    for (int ct = 0; ct < 4; ++ct)
      bcur[ct] = *reinterpret_cast<const bf16x8*>(
          ETp + (size_t)(jg0 + ct) * 8192 + lane * 8);
  }

  for (int jt = 0; jt < 8; ++jt) {
    const int wcol0 = colbase0 + jt * 256 + wave * 64;
    const int jgbase = wcol0 >> 4;
    f32x4 acc[2][4];
#pragma unroll
    for (int rt = 0; rt < 2; ++rt)
#pragma unroll
      for (int ct = 0; ct < 4; ++ct) {
        acc[rt][ct].x = 0.f; acc[rt][ct].y = 0.f; acc[rt][ct].z = 0.f; acc[rt][ct].w = 0.f;
      }
#pragma unroll
    for (int kk = 0; kk < 16; ++kk) {
      bf16x8 bnxt[4];
      if (kk < 15) {
#pragma unroll
        for (int ct = 0; ct < 4; ++ct)
          bnxt[ct] = *reinterpret_cast<const bf16x8*>(
              ETp + (size_t)(jgbase + ct) * 8192 + (kk + 1) * 512 + lane * 8);
      } else {
        const int jtn = (jt == 7) ? 7 : (jt + 1);
        const int jgn = (colbase0 + jtn * 256 + wave * 64) >> 4;
#pragma unroll
        for (int ct = 0; ct < 4; ++ct)
          bnxt[ct] = *reinterpret_cast<const bf16x8*>(
              ETp + (size_t)(jgn + ct) * 8192 + lane * 8);
      }
      const int inner = (kk << 6) + (hi << 4);
#pragma unroll
      for (int rt = 0; rt < 2; ++rt) {
        const int row = rt * 16 + lo16;
        const bf16x8 af = *reinterpret_cast<const bf16x8*>(
            reinterpret_cast<const char*>(sa) + row * 1024 + (inner ^ ((row & 7) << 4)));
#pragma unroll
        for (int ct = 0; ct < 4; ++ct)
          acc[rt][ct] = __builtin_amdgcn_mfma_f32_16x16x32_bf16(af, bcur[ct], acc[rt][ct], 0, 0, 0);
      }
#pragma unroll
      for (int ct = 0; ct < 4; ++ct) bcur[ct] = bnxt[ct];
    }
    // dump/scan: 8 passes (ct, h); slice [8 cols][stride 36 rows]
#pragma unroll
    for (int ct = 0; ct < 4; ++ct) {
#pragma unroll
      for (int h = 0; h < 2; ++h) {
        if ((lo16 >> 3) == h) {
#pragma unroll
          for (int rt = 0; rt < 2; ++rt)
            *reinterpret_cast<f32x4*>(sw + (lo16 & 7) * 36 + rt * 16 + hi * 4) = acc[rt][ct];
        }
        asm volatile("s_waitcnt lgkmcnt(0)" ::: "memory");
#pragma unroll
        for (int cc = 0; cc < 4; ++cc) {
          const float v = sw[(scang * 4 + cc) * 36 + scanr];
          const int col = wcol0 + ct * 16 + h * 8 + scang * 4 + cc;
          if (v > tv[5]) {
            tv[5] = v; ti[5] = col;
#pragma unroll
            for (int p = 5; p > 0; --p) {
              if (tv[p] > tv[p - 1]) {
                float tvt = tv[p]; tv[p] = tv[p - 1]; tv[p - 1] = tvt;
                int tit = ti[p]; ti[p] = ti[p - 1]; ti[p - 1] = tit;
              }
            }
          }
        }
        asm volatile("s_waitcnt lgkmcnt(0)" ::: "memory");
      }
    }
  }
  __syncthreads();
  // merge 8 partial lists (4 waves x 2 col-groups) per row; reuse A region
  float* mv = reinterpret_cast<float*>(sa);                 // [32][8][6]
  int* mi = reinterpret_cast<int*>(mv + 32 * 8 * 6);
  {
    const int li = wave * 2 + scang;
#pragma unroll
    for (int s = 0; s < 6; ++s) {
      mv[(scanr * 8 + li) * 6 + s] = tv[s];
      mi[(scanr * 8 + li) * 6 + s] = ti[s];
    }
  }
  __syncthreads();
  if (tid < 32) {
    int pq[8] = {0, 0, 0, 0, 0, 0, 0, 0};
    const int base = (split * N_NODES + grow0 + tid) * 6;
    for (int s = 0; s < 6; ++s) {
      float best = -3.4e38f;
      int bi = 0x7fffffff, bq = 0;
#pragma unroll
      for (int q = 0; q < 8; ++q) {
        if (pq[q] < 6) {
          const float v = mv[(tid * 8 + q) * 6 + pq[q]];
          const int ix = mi[(tid * 8 + q) * 6 + pq[q]];
          if (v > best || (v == best && ix < bi)) { best = v; bi = ix; bq = q; }
        }
      }
      tkv[base + s] = best;
      tki[base + s] = bi;
#pragma unroll
      for (int q = 0; q < 8; ++q) pq[q] += (bq == q) ? 1 : 0;
    }
  }
}

// merge the 4 j-split top-6 lists into final top-6
__global__ __launch_bounds__(256) void merge_topk4(const float* __restrict__ tkv,
                                                   const int* __restrict__ tki,
                                                   float* __restrict__ fw,
                                                   int* __restrict__ fi) {
  const int n = blockIdx.x * 256 + threadIdx.x;
  int pq[NSPLIT] = {0, 0, 0, 0};
  for (int s = 0; s < 6; ++s) {
    float best = -3.4e38f;
    int bi = 0x7fffffff, bq = 0;
#pragma unroll
    for (int q = 0; q < NSPLIT; ++q) {
      if (pq[q] < 6) {
        const float v = tkv[((size_t)q * N_NODES + n) * 6 + pq[q]];
        const int ix = tki[((size_t)q * N_NODES + n) * 6 + pq[q]];
        if (v > best || (v == best && ix < bi)) { best = v; bi = ix; bq = q; }
      }
    }
    fw[n * 6 + s] = best;
    fi[n * 6 + s] = bi;
#pragma unroll
    for (int q = 0; q < NSPLIT; ++q) pq[q] += (bq == q) ? 1 : 0;
  }
}

// ---------------------------------------------------------------------------
// Per-node neighbor aggregation; outputs Ub, Vb in bf16.
// ---------------------------------------------------------------------------
__global__ __launch_bounds__(256) void agg_kernel(const float* __restrict__ EH,
                                                  const float* __restrict__ ET,
                                                  const float* __restrict__ fw,
                                                  const int* __restrict__ fi,
                                                  unsigned short* __restrict__ Ub,
                                                  unsigned short* __restrict__ Vb) {
  __shared__ float sNb[KNB][DH];
  __shared__ float sred[4][8];
  __shared__ float ska[8];
  const int node = blockIdx.x;
  const int tid = threadIdx.x;
  float w[KNB];
  int idx[KNB];
#pragma unroll
  for (int k = 0; k < KNB; ++k) {
    w[k] = fw[node * KNB + k];
    idx[k] = fi[node * KNB + k];
  }
  float mx = w[0];
#pragma unroll
  for (int k = 1; k < KNB; ++k) mx = fmaxf(mx, w[k]);
  float pk[KNB];
  float se = 0.f;
#pragma unroll
  for (int k = 0; k < KNB; ++k) { pk[k] = expf(w[k] - mx); se += pk[k]; }
  const float inv_se = 1.f / se;
#pragma unroll
  for (int k = 0; k < KNB; ++k) pk[k] *= inv_se;
  for (int e = tid; e < KNB * DH; e += 256) {
    int k = e >> 9, d = e & 511;
    sNb[k][d] = ET[(size_t)idx[k] * DH + d];
  }
  __syncthreads();
  float eh[2];
  eh[0] = EH[(size_t)node * DH + tid];
  eh[1] = EH[(size_t)node * DH + tid + 256];
  float ka[KNB] = {0, 0, 0, 0, 0, 0};
#pragma unroll
  for (int t = 0; t < 2; ++t) {
    const int d = tid + t * 256;
    const float e_ = eh[t];
#pragma unroll
    for (int k = 0; k < KNB; ++k) {
      float Nb = sNb[k][d];
      float ehr = pk[k] * Nb + (1.f - pk[k]) * e_;
      float g = tanhf(e_ + ehr);
      ka[k] = fmaf(Nb, g, ka[k]);
    }
  }
#pragma unroll
  for (int k = 0; k < KNB; ++k) {
    float v = ka[k];
#pragma unroll
    for (int off = 32; off > 0; off >>= 1) v += __shfl_down(v, off, 64);
    if ((tid & 63) == 0) sred[tid >> 6][k] = v;
  }
  __syncthreads();
  if (tid < KNB) ska[tid] = sred[0][tid] + sred[1][tid] + sred[2][tid] + sred[3][tid];
  __syncthreads();
  float kav[KNB];
#pragma unroll
  for (int k = 0; k < KNB; ++k) kav[k] = ska[k];
  float kmx = kav[0];
#pragma unroll
  for (int k = 1; k < KNB; ++k) kmx = fmaxf(kmx, kav[k]);
  float kp[KNB];
  float ks = 0.f;
#pragma unroll
  for (int k = 0; k < KNB; ++k) { kp[k] = expf(kav[k] - kmx); ks += kp[k]; }
  const float inv_ks = 1.f / ks;
#pragma unroll
  for (int k = 0; k < KNB; ++k) kp[k] *= inv_ks;
#pragma unroll
  for (int t = 0; t < 2; ++t) {
    const int d = tid + t * 256;
    float eNh = 0.f;
#pragma unroll
    for (int k = 0; k < KNB; ++k) eNh = fmaf(kp[k], sNb[k][d], eNh);
    const float e_ = eh[t];
    Ub[(size_t)node * DH + d] = f2bf(e_ + eNh);
    Vb[(size_t)node * DH + d] = f2bf(e_ * eNh);
  }
}

// a[n] = dot(hid_bf16[n], att2_w) + att2_b ; one wave per node
__global__ __launch_bounds__(256) void att_dot(const unsigned short* __restrict__ HIDb,
                                               const float* __restrict__ w2,
                                               const float* __restrict__ b2,
                                               float* __restrict__ a) {
  const int wid = threadIdx.x >> 6, lane = threadIdx.x & 63;
  const int node = blockIdx.x * 4 + wid;
  const ushort4 h4 = *reinterpret_cast<const ushort4*>(HIDb + (size_t)node * 256 + lane * 4);
  const float4 w4 = *reinterpret_cast<const float4*>(w2 + lane * 4);
  float s = bf2f(h4.x) * w4.x + bf2f(h4.y) * w4.y + bf2f(h4.z) * w4.z + bf2f(h4.w) * w4.w;
#pragma unroll
  for (int off = 32; off > 0; off >>= 1) s += __shfl_down(s, off, 64);
  if (lane == 0) a[node] = s + b2[0];
}

// global softmax stats over a[8192]
__global__ __launch_bounds__(1024) void softmax_stats(const float* __restrict__ a,
                                                      float* __restrict__ st) {
  __shared__ float red[16];
  __shared__ float bc;
  const int tid = threadIdx.x;
  float mx = -3.4e38f;
  for (int i = tid; i < N_NODES; i += 1024) mx = fmaxf(mx, a[i]);
#pragma unroll
  for (int off = 32; off > 0; off >>= 1) mx = fmaxf(mx, __shfl_xor(mx, off, 64));
  if ((tid & 63) == 0) red[tid >> 6] = mx;
  __syncthreads();
  if (tid == 0) {
    float m = red[0];
    for (int i = 1; i < 16; ++i) m = fmaxf(m, red[i]);
    bc = m;
  }
  __syncthreads();
  const float gm = bc;
  float se = 0.f;
  for (int i = tid; i < N_NODES; i += 1024) se += expf(a[i] - gm);
#pragma unroll
  for (int off = 32; off > 0; off >>= 1) se += __shfl_xor(se, off, 64);
  if ((tid & 63) == 0) red[tid >> 6] = se;
  __syncthreads();
  if (tid == 0) {
    float s = 0.f;
    for (int i = 0; i < 16; ++i) s += red[i];
    st[0] = gm;
    st[1] = s;
  }
}

// h[c] = sum_n softmax(a)_n * emb_bf16[n][c]
__global__ __launch_bounds__(256) void readout(const unsigned short* __restrict__ EMBb,
                                               const float* __restrict__ a,
                                               const float* __restrict__ st,
                                               float* __restrict__ h) {
  __shared__ float sacc[4][64];
  const int tid = threadIdx.x;
  const int c = (blockIdx.x << 6) + (tid & 63);
  const int rsub = tid >> 6;
  const float mx = st[0], inv_se = 1.f / st[1];
  const int r0 = blockIdx.y << 8;
  float acc = 0.f;
  for (int i = 0; i < 64; ++i) {
    const int r = r0 + (i << 2) + rsub;
    const float g = expf(a[r] - mx);
    acc = fmaf(g, bf2f(EMBb[(size_t)r * DH + c]), acc);
  }
  sacc[rsub][tid & 63] = acc * inv_se;
  __syncthreads();
  if (rsub == 0) {
    float t = sacc[0][tid] + sacc[1][tid] + sacc[2][tid] + sacc[3][tid];
    atomicAdd(&h[c], t);
  }
}

// layernorm + final fc -> 2 logits
__global__ __launch_bounds__(512) void finalize(const float* __restrict__ h,
                                                const float* __restrict__ ln_g,
                                                const float* __restrict__ ln_b,
                                                const float* __restrict__ fc_w,
                                                const float* __restrict__ fc_b,
                                                float* __restrict__ out) {
  __shared__ float red0[8];
  __shared__ float red1[8];
  __shared__ float bc[2];
  const int tid = threadIdx.x;
  const int wid = tid >> 6, lane = tid & 63;
  const float v = h[tid];
  float s = v;
#pragma unroll
  for (int off = 32; off > 0; off >>= 1) s += __shfl_xor(s, off, 64);
  if (lane == 0) red0[wid] = s;
  __syncthreads();
  if (tid == 0) {
    float t = 0.f;
    for (int i = 0; i < 8; ++i) t += red0[i];
    bc[0] = t * (1.f / 512.f);
  }
  __syncthreads();
  const float mu = bc[0];
  const float dv = v - mu;
  s = dv * dv;
#pragma unroll
  for (int off = 32; off > 0; off >>= 1) s += __shfl_xor(s, off, 64);
  if (lane == 0) red0[wid] = s;
  __syncthreads();
  if (tid == 0) {
    float t = 0.f;
    for (int i = 0; i < 8; ++i) t += red0[i];
    bc[1] = t * (1.f / 512.f);
  }
  __syncthreads();
  const float var = bc[1];
  const float hn = dv / sqrtf(var + 1e-5f) * ln_g[tid] + ln_b[tid];
  float l0 = hn * fc_w[tid * 2 + 0];
  float l1 = hn * fc_w[tid * 2 + 1];
#pragma unroll
  for (int off = 32; off > 0; off >>= 1) {
    l0 += __shfl_xor(l0, off, 64);
    l1 += __shfl_xor(l1, off, 64);
  }
  if (lane == 0) { red0[wid] = l0; red1[wid] = l1; }
  __syncthreads();
  if (tid == 0) {
    float t0 = 0.f, t1 = 0.f;
    for (int i = 0; i < 8; ++i) { t0 += red0[i]; t1 += red1[i]; }
    out[0] = t0 + fc_b[0];
    out[1] = t1 + fc_b[1];
  }
}

// ---------------------------------------------------------------------------
extern "C" void kernel_launch(void* const* d_in, const int* in_sizes, int n_in,
                              void* d_out, int out_size, void* d_ws, size_t ws_size,
                              hipStream_t stream) {
  const float* x_s    = (const float*)d_in[0];
  const float* fc1_w  = (const float*)d_in[1];
  const float* fc1_b  = (const float*)d_in[2];
  const float* wh_w   = (const float*)d_in[3];
  const float* wh_b   = (const float*)d_in[4];
  const float* wt_w   = (const float*)d_in[5];
  const float* wt_b   = (const float*)d_in[6];
  const float* l1_w   = (const float*)d_in[7];
  const float* l1_b   = (const float*)d_in[8];
  const float* l2_w   = (const float*)d_in[9];
  const float* l2_b   = (const float*)d_in[10];
  const float* att1_w = (const float*)d_in[11];
  const float* att1_b = (const float*)d_in[12];
  const float* att2_w = (const float*)d_in[13];
  const float* att2_b = (const float*)d_in[14];
  const float* ln_g   = (const float*)d_in[15];
  const float* ln_b   = (const float*)d_in[16];
  const float* fc_w   = (const float*)d_in[17];
  const float* fc_b   = (const float*)d_in[18];

  float* ws = (float*)d_ws;
  const size_t BIG = (size_t)N_NODES * DH;  // 4,194,304
  float* B1 = ws;                                        // x fp32 -> e_h fp32
  float* B2 = ws + BIG;                                  // e_t fp32
  unsigned short* R1 = (unsigned short*)(ws + 2 * BIG);  // xsb -> EHb -> Ub -> hidb
  unsigned short* R2 = R1 + BIG;                          // xb -> Vb
  unsigned short* R3 = R2 + BIG;                          // ETp (packed) -> embb
  unsigned short* WT = R3 + BIG;                          // transposed bf16 weights
  float* tail = (float*)(WT + 1376256);
  float* tkv    = tail;                          // 4*8192*6
  int*   tki    = (int*)(tkv + NSPLIT * N_NODES * 6);
  float* fwv    = (float*)(tki + NSPLIT * N_NODES * 6);
  int*   fiv    = (int*)(fwv + N_NODES * 6);
  float* colsum = (float*)(fiv + N_NODES * 6);
  float* av     = colsum + DH;
  float* stats  = av + N_NODES;
  float* hbuf   = stats + 16;

  unsigned short* fc1t  = WT + 0;
  unsigned short* wht   = WT + 196608;
  unsigned short* wtt   = WT + 458752;
  unsigned short* l1t   = WT + 720896;
  unsigned short* l2t   = WT + 983040;
  unsigned short* att1t = WT + 1245184;

  const float kscale = 0.044194173824159216f;  // 512^-0.5

  // 0. prep
  prep_weights<<<5376, 256, 0, stream>>>(fc1_w, wh_w, wt_w, l1_w, l2_w, att1_w, WT);
  convert_xs<<<3072, 256, 0, stream>>>(x_s, R1);
  // 1. x = lrelu(xsb @ fc1t^T + b) -> B1 fp32
  gemm128<1, 1, 0><<<dim3(4, 64), 256, 0, stream>>>(
      R1, fc1t, fc1_b, B1, nullptr, DIN, DH);
  // 2. mean-mix -> xb bf16 (R2)
  hipMemsetAsync(colsum, 0, DH * sizeof(float), stream);
  colsum_kernel<<<64, 256, 0, stream>>>(B1, colsum);
  mix_kernel<<<4096, 256, 0, stream>>>(B1, colsum, R2);
  // 3. fused e_h/e_t: e_h -> B1 fp32 + EHb*kscale (R1); e_t -> B2 fp32 + ETp (R3)
  gemm128_ehet<<<dim3(4, 64), 256, 0, stream>>>(
      R2, wht, wtt, wh_b, wt_b, B1, R1, B2, R3, kscale);
  // 4. scoring v6 (4 blocks/CU occupancy) + merge
  score_topk_v6<<<1024, 256, 0, stream>>>(R1, R3, tkv, tki);
  merge_topk4<<<32, 256, 0, stream>>>(tkv, tki, fwv, fiv);
  // 5. aggregation -> Ub (R1), Vb (R2)
  agg_kernel<<<N_NODES, 256, 0, stream>>>(B1, B2, fwv, fiv, R1, R2);
  // 6. fused l1/l2 -> embb (R3)
  gemm128_l1l2<<<dim3(4, 64), 256, 0, stream>>>(
      R1, R2, l1t, l2t, l1_b, l2_b, R3);
  // 7. attention readout
  gemm128<1, 0, 1><<<dim3(2, 64), 256, 0, stream>>>(
      R3, att1t, att1_b, nullptr, R1, DH, 256);
  att_dot<<<2048, 256, 0, stream>>>(R1, att2_w, att2_b, av);
  softmax_stats<<<1, 1024, 0, stream>>>(av, stats);
  hipMemsetAsync(hbuf, 0, DH * sizeof(float), stream);
  readout<<<dim3(8, 32), 256, 0, stream>>>(R3, av, stats, hbuf);
  // 8. layernorm + logits
  finalize<<<1, 512, 0, stream>>>(hbuf, ln_g, ln_b, fc_w, fc_b, (float*)d_out);
}

// Round 10
// 336.414 us; speedup vs baseline: 1.2831x; 1.0616x over previous
//
#include <hip/hip_runtime.h>
#include <hip/hip_bf16.h>
#include <math.h>

#define N_NODES 8192
#define DIN 384
#define DH 512
#define KNB 6
#define NEG_SLOPE 0.01f
#define NSPLIT 4
#define KSCALE 0.044194173824159216f  // 512^-0.5

typedef __attribute__((ext_vector_type(8))) short bf16x8;
typedef __attribute__((ext_vector_type(4))) float f32x4;

__device__ __forceinline__ unsigned short f2bf(float x) {
  unsigned int u = __float_as_uint(x);
  unsigned int r = (u + 0x7fffu + ((u >> 16) & 1u)) >> 16;  // RNE
  return (unsigned short)r;
}
__device__ __forceinline__ float bf2f(unsigned short u) {
  return __uint_as_float(((unsigned int)u) << 16);
}

// ---------------------------------------------------------------------------
// Weight prep v2: LDS 64x64 tile transpose, coalesced reads AND writes.
// 336 tiles total across the 6 weights.
// ---------------------------------------------------------------------------
__global__ __launch_bounds__(256) void prep_weights_t(
    const float* __restrict__ w0, const float* __restrict__ w1,
    const float* __restrict__ w2, const float* __restrict__ w3,
    const float* __restrict__ w4, const float* __restrict__ w5,
    unsigned short* __restrict__ pool) {
  __shared__ float tile[64][65];
  const int t = blockIdx.x;
  // tile counts: w0:48 w1..w4:64 each w5:32 (cum 48,112,176,240,304,336)
  const float* src; int off, Kw, Nw, tl;
  if (t < 48)       { src = w0; off = 0;       Kw = 384; Nw = 512; tl = t; }
  else if (t < 112) { src = w1; off = 196608;  Kw = 512; Nw = 512; tl = t - 48; }
  else if (t < 176) { src = w2; off = 458752;  Kw = 512; Nw = 512; tl = t - 112; }
  else if (t < 240) { src = w3; off = 720896;  Kw = 512; Nw = 512; tl = t - 176; }
  else if (t < 304) { src = w4; off = 983040;  Kw = 512; Nw = 512; tl = t - 240; }
  else              { src = w5; off = 1245184; Kw = 512; Nw = 256; tl = t - 304; }
  const int nk = Kw >> 6;
  const int kbase = (tl % nk) << 6, nbase = (tl / nk) << 6;
  const int tx = threadIdx.x & 63, ty = threadIdx.x >> 6;
#pragma unroll
  for (int i = 0; i < 16; ++i) {
    const int r = i * 4 + ty;
    tile[r][tx] = src[(size_t)(kbase + r) * Nw + nbase + tx];
  }
  __syncthreads();
#pragma unroll
  for (int i = 0; i < 16; ++i) {
    const int rr = i * 4 + ty;
    pool[(size_t)off + (size_t)(nbase + rr) * Kw + kbase + tx] = f2bf(tile[tx][rr]);
  }
}

// x_s fp32 -> bf16
__global__ __launch_bounds__(256) void convert_xs(const float* __restrict__ xs,
                                                  unsigned short* __restrict__ out) {
  const size_t i = ((size_t)blockIdx.x * 256 + threadIdx.x) * 4;
  const float4 v = *reinterpret_cast<const float4*>(xs + i);
  ushort4 o;
  o.x = f2bf(v.x); o.y = f2bf(v.y); o.z = f2bf(v.z); o.w = f2bf(v.w);
  *reinterpret_cast<ushort4*>(out + i) = o;
}

// ---------------------------------------------------------------------------
// 128x128-tile bf16 MFMA GEMM, 512 threads / 8 waves (64x32 per wave).
// 2 waves/SIMD at grid=256 (vs 1 for the 4-wave version).
// ---------------------------------------------------------------------------
template <int ACT, int WF32, int WBF16>
__global__ __launch_bounds__(512) void gemm128(
    const unsigned short* __restrict__ A, const unsigned short* __restrict__ Wt,
    const float* __restrict__ bias, float* __restrict__ C,
    unsigned short* __restrict__ Cb, int K, int N) {
  __shared__ unsigned short sa[128 * 64];
  __shared__ unsigned short sb[128 * 64];
  const int tid = threadIdx.x;
  const int wave = tid >> 6, lane = tid & 63;
  const int lo16 = lane & 15, hi = lane >> 4;
  const int wr = (wave >> 2) << 6, wc = (wave & 3) << 5;
  const int row0 = blockIdx.y << 7, col0 = blockIdx.x << 7;
  f32x4 acc[4][2];
#pragma unroll
  for (int rt = 0; rt < 4; ++rt)
#pragma unroll
    for (int ct = 0; ct < 2; ++ct) { acc[rt][ct].x = 0.f; acc[rt][ct].y = 0.f; acc[rt][ct].z = 0.f; acc[rt][ct].w = 0.f; }
  for (int k0 = 0; k0 < K; k0 += 64) {
    __syncthreads();
#pragma unroll
    for (int i = 0; i < 2; ++i) {
      const int c = i * 512 + tid;  // 0..1023
      const int r = c >> 3, i8 = c & 7;
      const int byte = r * 128 + ((i8 * 16) ^ ((r & 7) << 4));
      *reinterpret_cast<bf16x8*>(reinterpret_cast<char*>(sa) + byte) =
          *reinterpret_cast<const bf16x8*>(A + (size_t)(row0 + r) * K + k0 + i8 * 8);
      *reinterpret_cast<bf16x8*>(reinterpret_cast<char*>(sb) + byte) =
          *reinterpret_cast<const bf16x8*>(Wt + (size_t)(col0 + r) * K + k0 + i8 * 8);
    }
    __syncthreads();
#pragma unroll
    for (int kk2 = 0; kk2 < 2; ++kk2) {
      const int inner = (kk2 << 6) + (hi << 4);
      bf16x8 af[4], bf[2];
#pragma unroll
      for (int t = 0; t < 4; ++t) {
        const int row = wr + t * 16 + lo16;
        af[t] = *reinterpret_cast<const bf16x8*>(reinterpret_cast<const char*>(sa) + row * 128 + (inner ^ ((row & 7) << 4)));
      }
#pragma unroll
      for (int t = 0; t < 2; ++t) {
        const int col = wc + t * 16 + lo16;
        bf[t] = *reinterpret_cast<const bf16x8*>(reinterpret_cast<const char*>(sb) + col * 128 + (inner ^ ((col & 7) << 4)));
      }
#pragma unroll
      for (int rt = 0; rt < 4; ++rt)
#pragma unroll
        for (int ct = 0; ct < 2; ++ct)
          acc[rt][ct] = __builtin_amdgcn_mfma_f32_16x16x32_bf16(af[rt], bf[ct], acc[rt][ct], 0, 0, 0);
    }
  }
#pragma unroll
  for (int ct = 0; ct < 2; ++ct) {
    const int colg = col0 + wc + ct * 16 + lo16;
    const float bv = bias[colg];
#pragma unroll
    for (int rt = 0; rt < 4; ++rt) {
#pragma unroll
      for (int j = 0; j < 4; ++j) {
        const int r = row0 + wr + rt * 16 + hi * 4 + j;
        float v = acc[rt][ct][j] + bv;
        if (ACT) v = v > 0.f ? v : NEG_SLOPE * v;
        if (WF32) C[(size_t)r * N + colg] = v;
        if (WBF16) Cb[(size_t)r * N + colg] = f2bf(v);
      }
    }
  }
}

// ---------------------------------------------------------------------------
// Fused e_h/e_t GEMM (512 thr, 8 waves). Outputs: EHb (bf16 row-major,
// UNSCALED), ETp (bf16 frag-packed), ETb (bf16 row-major). No fp32 outputs.
// ---------------------------------------------------------------------------
__global__ __launch_bounds__(512) void gemm128_ehet(
    const unsigned short* __restrict__ A,
    const unsigned short* __restrict__ W1, const unsigned short* __restrict__ W2,
    const float* __restrict__ b1, const float* __restrict__ b2,
    unsigned short* __restrict__ EHb, unsigned short* __restrict__ ETp,
    unsigned short* __restrict__ ETb) {
  __shared__ unsigned short sa[128 * 64];
  __shared__ unsigned short sb1[128 * 64];
  __shared__ unsigned short sb2[128 * 64];
  const int tid = threadIdx.x;
  const int wave = tid >> 6, lane = tid & 63;
  const int lo16 = lane & 15, hi = lane >> 4;
  const int wr = (wave >> 2) << 6, wc = (wave & 3) << 5;
  const int row0 = blockIdx.y << 7, col0 = blockIdx.x << 7;
  f32x4 au[4][2], av[4][2];
#pragma unroll
  for (int rt = 0; rt < 4; ++rt)
#pragma unroll
    for (int ct = 0; ct < 2; ++ct) {
      au[rt][ct].x = 0.f; au[rt][ct].y = 0.f; au[rt][ct].z = 0.f; au[rt][ct].w = 0.f;
      av[rt][ct].x = 0.f; av[rt][ct].y = 0.f; av[rt][ct].z = 0.f; av[rt][ct].w = 0.f;
    }
  for (int k0 = 0; k0 < DH; k0 += 64) {
    __syncthreads();
#pragma unroll
    for (int i = 0; i < 2; ++i) {
      const int c = i * 512 + tid;
      const int r = c >> 3, i8 = c & 7;
      const int byte = r * 128 + ((i8 * 16) ^ ((r & 7) << 4));
      *reinterpret_cast<bf16x8*>(reinterpret_cast<char*>(sa) + byte) =
          *reinterpret_cast<const bf16x8*>(A + (size_t)(row0 + r) * DH + k0 + i8 * 8);
      *reinterpret_cast<bf16x8*>(reinterpret_cast<char*>(sb1) + byte) =
          *reinterpret_cast<const bf16x8*>(W1 + (size_t)(col0 + r) * DH + k0 + i8 * 8);
      *reinterpret_cast<bf16x8*>(reinterpret_cast<char*>(sb2) + byte) =
          *reinterpret_cast<const bf16x8*>(W2 + (size_t)(col0 + r) * DH + k0 + i8 * 8);
    }
    __syncthreads();
#pragma unroll
    for (int kk2 = 0; kk2 < 2; ++kk2) {
      const int inner = (kk2 << 6) + (hi << 4);
      bf16x8 af[4], bf1[2], bf2[2];
#pragma unroll
      for (int t = 0; t < 4; ++t) {
        const int row = wr + t * 16 + lo16;
        af[t] = *reinterpret_cast<const bf16x8*>(reinterpret_cast<const char*>(sa) + row * 128 + (inner ^ ((row & 7) << 4)));
      }
#pragma unroll
      for (int t = 0; t < 2; ++t) {
        const int col = wc + t * 16 + lo16;
        const int boff = col * 128 + (inner ^ ((col & 7) << 4));
        bf1[t] = *reinterpret_cast<const bf16x8*>(reinterpret_cast<const char*>(sb1) + boff);
        bf2[t] = *reinterpret_cast<const bf16x8*>(reinterpret_cast<const char*>(sb2) + boff);
      }
#pragma unroll
      for (int rt = 0; rt < 4; ++rt)
#pragma unroll
        for (int ct = 0; ct < 2; ++ct) {
          au[rt][ct] = __builtin_amdgcn_mfma_f32_16x16x32_bf16(af[rt], bf1[ct], au[rt][ct], 0, 0, 0);
          av[rt][ct] = __builtin_amdgcn_mfma_f32_16x16x32_bf16(af[rt], bf2[ct], av[rt][ct], 0, 0, 0);
        }
    }
  }
#pragma unroll
  for (int ct = 0; ct < 2; ++ct) {
    const int colg = col0 + wc + ct * 16 + lo16;
    const float bv1 = b1[colg], bv2 = b2[colg];
#pragma unroll
    for (int rt = 0; rt < 4; ++rt) {
#pragma unroll
      for (int j = 0; j < 4; ++j) {
        const int r = row0 + wr + rt * 16 + hi * 4 + j;
        const float vh = au[rt][ct][j] + bv1;
        const float vt = av[rt][ct][j] + bv2;
        EHb[(size_t)r * DH + colg] = f2bf(vh);   // UNSCALED (kscale applied post-topk)
        ETb[(size_t)r * DH + colg] = f2bf(vt);
        const size_t idx = (size_t)(r >> 4) * 8192 + (size_t)(colg >> 5) * 512 +
                           (size_t)((((colg & 31) >> 3) * 16 + (r & 15)) * 8) + (colg & 7);
        ETp[idx] = f2bf(vt);
      }
    }
  }
}

// ---------------------------------------------------------------------------
// Fused l1/l2 GEMM (512 thr): emb = lrelu(U@l1+b1) + lrelu(V@l2+b2), bf16 out.
// ---------------------------------------------------------------------------
__global__ __launch_bounds__(512) void gemm128_l1l2(
    const unsigned short* __restrict__ Ub, const unsigned short* __restrict__ Vb,
    const unsigned short* __restrict__ W1, const unsigned short* __restrict__ W2,
    const float* __restrict__ b1, const float* __restrict__ b2,
    unsigned short* __restrict__ EMBb) {
  __shared__ unsigned short sa1[128 * 64];
  __shared__ unsigned short sa2[128 * 64];
  __shared__ unsigned short sb1[128 * 64];
  __shared__ unsigned short sb2[128 * 64];
  const int tid = threadIdx.x;
  const int wave = tid >> 6, lane = tid & 63;
  const int lo16 = lane & 15, hi = lane >> 4;
  const int wr = (wave >> 2) << 6, wc = (wave & 3) << 5;
  const int row0 = blockIdx.y << 7, col0 = blockIdx.x << 7;
  f32x4 au[4][2], av[4][2];
#pragma unroll
  for (int rt = 0; rt < 4; ++rt)
#pragma unroll
    for (int ct = 0; ct < 2; ++ct) {
      au[rt][ct].x = 0.f; au[rt][ct].y = 0.f; au[rt][ct].z = 0.f; au[rt][ct].w = 0.f;
      av[rt][ct].x = 0.f; av[rt][ct].y = 0.f; av[rt][ct].z = 0.f; av[rt][ct].w = 0.f;
    }
  for (int k0 = 0; k0 < DH; k0 += 64) {
    __syncthreads();
#pragma unroll
    for (int i = 0; i < 2; ++i) {
      const int c = i * 512 + tid;
      const int r = c >> 3, i8 = c & 7;
      const int byte = r * 128 + ((i8 * 16) ^ ((r & 7) << 4));
      *reinterpret_cast<bf16x8*>(reinterpret_cast<char*>(sa1) + byte) =
          *reinterpret_cast<const bf16x8*>(Ub + (size_t)(row0 + r) * DH + k0 + i8 * 8);
      *reinterpret_cast<bf16x8*>(reinterpret_cast<char*>(sa2) + byte) =
          *reinterpret_cast<const bf16x8*>(Vb + (size_t)(row0 + r) * DH + k0 + i8 * 8);
      *reinterpret_cast<bf16x8*>(reinterpret_cast<char*>(sb1) + byte) =
          *reinterpret_cast<const bf16x8*>(W1 + (size_t)(col0 + r) * DH + k0 + i8 * 8);
      *reinterpret_cast<bf16x8*>(reinterpret_cast<char*>(sb2) + byte) =
          *reinterpret_cast<const bf16x8*>(W2 + (size_t)(col0 + r) * DH + k0 + i8 * 8);
    }
    __syncthreads();
#pragma unroll
    for (int kk2 = 0; kk2 < 2; ++kk2) {
      const int inner = (kk2 << 6) + (hi << 4);
      bf16x8 a1[4], a2[4], bf1[2], bf2[2];
#pragma unroll
      for (int t = 0; t < 4; ++t) {
        const int row = wr + t * 16 + lo16;
        const int aoff = row * 128 + (inner ^ ((row & 7) << 4));
        a1[t] = *reinterpret_cast<const bf16x8*>(reinterpret_cast<const char*>(sa1) + aoff);
        a2[t] = *reinterpret_cast<const bf16x8*>(reinterpret_cast<const char*>(sa2) + aoff);
      }
#pragma unroll
      for (int t = 0; t < 2; ++t) {
        const int col = wc + t * 16 + lo16;
        const int boff = col * 128 + (inner ^ ((col & 7) << 4));
        bf1[t] = *reinterpret_cast<const bf16x8*>(reinterpret_cast<const char*>(sb1) + boff);
        bf2[t] = *reinterpret_cast<const bf16x8*>(reinterpret_cast<const char*>(sb2) + boff);
      }
#pragma unroll
      for (int rt = 0; rt < 4; ++rt)
#pragma unroll
        for (int ct = 0; ct < 2; ++ct) {
          au[rt][ct] = __builtin_amdgcn_mfma_f32_16x16x32_bf16(a1[rt], bf1[ct], au[rt][ct], 0, 0, 0);
          av[rt][ct] = __builtin_amdgcn_mfma_f32_16x16x32_bf16(a2[rt], bf2[ct], av[rt][ct], 0, 0, 0);
        }
    }
  }
#pragma unroll
  for (int ct = 0; ct < 2; ++ct) {
    const int colg = col0 + wc + ct * 16 + lo16;
    const float bv1 = b1[colg], bv2 = b2[colg];
#pragma unroll
    for (int rt = 0; rt < 4; ++rt) {
#pragma unroll
      for (int j = 0; j < 4; ++j) {
        const int r = row0 + wr + rt * 16 + hi * 4 + j;
        float u = au[rt][ct][j] + bv1;
        float v = av[rt][ct][j] + bv2;
        u = u > 0.f ? u : NEG_SLOPE * u;
        v = v > 0.f ? v : NEG_SLOPE * v;
        EMBb[(size_t)r * DH + colg] = f2bf(u + v);
      }
    }
  }
}

// ---------------------------------------------------------------------------
// Column sums of X[8192 x 512]
// ---------------------------------------------------------------------------
__global__ __launch_bounds__(256) void colsum_kernel(const float* __restrict__ X,
                                                     float* __restrict__ cs) {
  const int tid = threadIdx.x;
  float s0 = 0.f, s1 = 0.f;
  const int r0 = blockIdx.x * 128;
  for (int r = r0; r < r0 + 128; ++r) {
    s0 += X[(size_t)r * DH + tid];
    s1 += X[(size_t)r * DH + tid + 256];
  }
  atomicAdd(&cs[tid], s0);
  atomicAdd(&cs[tid + 256], s1);
}

// x = (x + colmean) * 0.5 ; emit bf16 copy only
__global__ __launch_bounds__(256) void mix_kernel(float* __restrict__ X,
                                                  const float* __restrict__ cs,
                                                  unsigned short* __restrict__ Xb) {
  const size_t gid = (size_t)blockIdx.x * 256 + threadIdx.x;
  const int c4 = ((int)gid & 127) << 2;
  float4 x = *reinterpret_cast<float4*>(X + gid * 4);
  const float inv = 1.f / 8192.f;
  x.x = (x.x + cs[c4 + 0] * inv) * 0.5f;
  x.y = (x.y + cs[c4 + 1] * inv) * 0.5f;
  x.z = (x.z + cs[c4 + 2] * inv) * 0.5f;
  x.w = (x.w + cs[c4 + 3] * inv) * 0.5f;
  ushort4 o;
  o.x = f2bf(x.x); o.y = f2bf(x.y); o.z = f2bf(x.z); o.w = f2bf(x.w);
  *reinterpret_cast<ushort4*>(Xb + gid * 4) = o;
}

// ---------------------------------------------------------------------------
// MFMA scoring + streaming top-6 (r9-proven v6). EHb unscaled; scores are
// unscaled (monotonic in the scaled ones), kscale applied in merge.
// ---------------------------------------------------------------------------
__global__ __launch_bounds__(256, 4) void score_topk_v6(
    const unsigned short* __restrict__ EHb, const unsigned short* __restrict__ ETp,
    float* __restrict__ tkv, int* __restrict__ tki) {
  __shared__ unsigned short sa[32 * 512];
  __shared__ float swb[4][8 * 36];
  const int tid = threadIdx.x;
  const int wave = tid >> 6, lane = tid & 63;
  const int lo16 = lane & 15, hi = lane >> 4;
  const int bid = blockIdx.x;
  const int split = (bid & 7) >> 1;
  const int rowblk = ((bid >> 3) << 1) | (bid & 1);
  const int grow0 = rowblk << 5;
  const int colbase0 = split << 11;

#pragma unroll
  for (int i = 0; i < 8; ++i) {
    const int c = i * 256 + tid;
    const int row = c >> 6, i8 = c & 63;
    const bf16x8 v = *reinterpret_cast<const bf16x8*>(
        EHb + (size_t)(grow0 + row) * DH + i8 * 8);
    const int byte = row * 1024 + ((i8 * 16) ^ ((row & 7) << 4));
    *reinterpret_cast<bf16x8*>(reinterpret_cast<char*>(sa) + byte) = v;
  }
  __syncthreads();

  float tv[6];
  int ti[6];
#pragma unroll
  for (int s = 0; s < 6; ++s) { tv[s] = -3.4e38f; ti[s] = 0; }

  float* sw = swb[wave];
  const int scanr = lane & 31, scang = lane >> 5;

  bf16x8 bcur[4];
  {
    const int jg0 = (colbase0 + wave * 64) >> 4;
#pragma unroll
    for (int ct = 0; ct < 4; ++ct)
      bcur[ct] = *reinterpret_cast<const bf16x8*>(
          ETp + (size_t)(jg0 + ct) * 8192 + lane * 8);
  }

  for (int jt = 0; jt < 8; ++jt) {
    const int wcol0 = colbase0 + jt * 256 + wave * 64;
    const int jgbase = wcol0 >> 4;
    f32x4 acc[2][4];
#pragma unroll
    for (int rt = 0; rt < 2; ++rt)
#pragma unroll
      for (int ct = 0; ct < 4; ++ct) {
        acc[rt][ct].x = 0.f; acc[rt][ct].y = 0.f; acc[rt][ct].z = 0.f; acc[rt][ct].w = 0.f;
      }
#pragma unroll
    for (int kk = 0; kk < 16; ++kk) {
      bf16x8 bnxt[4];
      if (kk < 15) {
#pragma unroll
        for (int ct = 0; ct < 4; ++ct)
          bnxt[ct] = *reinterpret_cast<const bf16x8*>(
              ETp + (size_t)(jgbase + ct) * 8192 + (kk + 1) * 512 + lane * 8);
      } else {
        const int jtn = (jt == 7) ? 7 : (jt + 1);
        const int jgn = (colbase0 + jtn * 256 + wave * 64) >> 4;
#pragma unroll
        for (int ct = 0; ct < 4; ++ct)
          bnxt[ct] = *reinterpret_cast<const bf16x8*>(
              ETp + (size_t)(jgn + ct) * 8192 + lane * 8);
      }
      const int inner = (kk << 6) + (hi << 4);
#pragma unroll
      for (int rt = 0; rt < 2; ++rt) {
        const int row = rt * 16 + lo16;
        const bf16x8 af = *reinterpret_cast<const bf16x8*>(
            reinterpret_cast<const char*>(sa) + row * 1024 + (inner ^ ((row & 7) << 4)));
#pragma unroll
        for (int ct = 0; ct < 4; ++ct)
          acc[rt][ct] = __builtin_amdgcn_mfma_f32_16x16x32_bf16(af, bcur[ct], acc[rt][ct], 0, 0, 0);
      }
#pragma unroll
      for (int ct = 0; ct < 4; ++ct) bcur[ct] = bnxt[ct];
    }
#pragma unroll
    for (int ct = 0; ct < 4; ++ct) {
#pragma unroll
      for (int h = 0; h < 2; ++h) {
        if ((lo16 >> 3) == h) {
#pragma unroll
          for (int rt = 0; rt < 2; ++rt)
            *reinterpret_cast<f32x4*>(sw + (lo16 & 7) * 36 + rt * 16 + hi * 4) = acc[rt][ct];
        }
        asm volatile("s_waitcnt lgkmcnt(0)" ::: "memory");
#pragma unroll
        for (int cc = 0; cc < 4; ++cc) {
          const float v = sw[(scang * 4 + cc) * 36 + scanr];
          const int col = wcol0 + ct * 16 + h * 8 + scang * 4 + cc;
          if (v > tv[5]) {
            tv[5] = v; ti[5] = col;
#pragma unroll
            for (int p = 5; p > 0; --p) {
              if (tv[p] > tv[p - 1]) {
                float tvt = tv[p]; tv[p] = tv[p - 1]; tv[p - 1] = tvt;
                int tit = ti[p]; ti[p] = ti[p - 1]; ti[p - 1] = tit;
              }
            }
          }
        }
        asm volatile("s_waitcnt lgkmcnt(0)" ::: "memory");
      }
    }
  }
  __syncthreads();
  float* mv = reinterpret_cast<float*>(sa);
  int* mi = reinterpret_cast<int*>(mv + 32 * 8 * 6);
  {
    const int li = wave * 2 + scang;
#pragma unroll
    for (int s = 0; s < 6; ++s) {
      mv[(scanr * 8 + li) * 6 + s] = tv[s];
      mi[(scanr * 8 + li) * 6 + s] = ti[s];
    }
  }
  __syncthreads();
  if (tid < 32) {
    int pq[8] = {0, 0, 0, 0, 0, 0, 0, 0};
    const int base = (split * N_NODES + grow0 + tid) * 6;
    for (int s = 0; s < 6; ++s) {
      float best = -3.4e38f;
      int bi = 0x7fffffff, bq = 0;
#pragma unroll
      for (int q = 0; q < 8; ++q) {
        if (pq[q] < 6) {
          const float v = mv[(tid * 8 + q) * 6 + pq[q]];
          const int ix = mi[(tid * 8 + q) * 6 + pq[q]];
          if (v > best || (v == best && ix < bi)) { best = v; bi = ix; bq = q; }
        }
      }
      tkv[base + s] = best;
      tki[base + s] = bi;
#pragma unroll
      for (int q = 0; q < 8; ++q) pq[q] += (bq == q) ? 1 : 0;
    }
  }
}

// merge the 4 j-split top-6 lists; apply kscale to the winning scores.
__global__ __launch_bounds__(256) void merge_topk4(const float* __restrict__ tkv,
                                                   const int* __restrict__ tki,
                                                   float* __restrict__ fw,
                                                   int* __restrict__ fi) {
  const int n = blockIdx.x * 256 + threadIdx.x;
  int pq[NSPLIT] = {0, 0, 0, 0};
  for (int s = 0; s < 6; ++s) {
    float best = -3.4e38f;
    int bi = 0x7fffffff, bq = 0;
#pragma unroll
    for (int q = 0; q < NSPLIT; ++q) {
      if (pq[q] < 6) {
        const float v = tkv[((size_t)q * N_NODES + n) * 6 + pq[q]];
        const int ix = tki[((size_t)q * N_NODES + n) * 6 + pq[q]];
        if (v > best || (v == best && ix < bi)) { best = v; bi = ix; bq = q; }
      }
    }
    fw[n * 6 + s] = best * KSCALE;
    fi[n * 6 + s] = bi;
#pragma unroll
    for (int q = 0; q < NSPLIT; ++q) pq[q] += (bq == q) ? 1 : 0;
  }
}

// ---------------------------------------------------------------------------
// Per-node neighbor aggregation; all-bf16 inputs (EHb unscaled, ETb row-major).
// ---------------------------------------------------------------------------
__global__ __launch_bounds__(256) void agg_kernel(const unsigned short* __restrict__ EHb,
                                                  const unsigned short* __restrict__ ETb,
                                                  const float* __restrict__ fw,
                                                  const int* __restrict__ fi,
                                                  unsigned short* __restrict__ Ub,
                                                  unsigned short* __restrict__ Vb) {
  __shared__ float sNb[KNB][DH];
  __shared__ float sred[4][8];
  __shared__ float ska[8];
  const int node = blockIdx.x;
  const int tid = threadIdx.x;
  float w[KNB];
  int idx[KNB];
#pragma unroll
  for (int k = 0; k < KNB; ++k) {
    w[k] = fw[node * KNB + k];
    idx[k] = fi[node * KNB + k];
  }
  float mx = w[0];
#pragma unroll
  for (int k = 1; k < KNB; ++k) mx = fmaxf(mx, w[k]);
  float pk[KNB];
  float se = 0.f;
#pragma unroll
  for (int k = 0; k < KNB; ++k) { pk[k] = expf(w[k] - mx); se += pk[k]; }
  const float inv_se = 1.f / se;
#pragma unroll
  for (int k = 0; k < KNB; ++k) pk[k] *= inv_se;
  // gather 6 neighbor rows (bf16, coalesced ushort2) -> LDS fp32
#pragma unroll
  for (int k = 0; k < KNB; ++k) {
    const ushort2 v = *reinterpret_cast<const ushort2*>(ETb + (size_t)idx[k] * DH + tid * 2);
    sNb[k][tid * 2] = bf2f(v.x);
    sNb[k][tid * 2 + 1] = bf2f(v.y);
  }
  __syncthreads();
  float eh[2];
  eh[0] = bf2f(EHb[(size_t)node * DH + tid]);
  eh[1] = bf2f(EHb[(size_t)node * DH + tid + 256]);
  float ka[KNB] = {0, 0, 0, 0, 0, 0};
#pragma unroll
  for (int t = 0; t < 2; ++t) {
    const int d = tid + t * 256;
    const float e_ = eh[t];
#pragma unroll
    for (int k = 0; k < KNB; ++k) {
      float Nb = sNb[k][d];
      float ehr = pk[k] * Nb + (1.f - pk[k]) * e_;
      float g = tanhf(e_ + ehr);
      ka[k] = fmaf(Nb, g, ka[k]);
    }
  }
#pragma unroll
  for (int k = 0; k < KNB; ++k) {
    float v = ka[k];
#pragma unroll
    for (int off = 32; off > 0; off >>= 1) v += __shfl_down(v, off, 64);
    if ((tid & 63) == 0) sred[tid >> 6][k] = v;
  }
  __syncthreads();
  if (tid < KNB) ska[tid] = sred[0][tid] + sred[1][tid] + sred[2][tid] + sred[3][tid];
  __syncthreads();
  float kav[KNB];
#pragma unroll
  for (int k = 0; k < KNB; ++k) kav[k] = ska[k];
  float kmx = kav[0];
#pragma unroll
  for (int k = 1; k < KNB; ++k) kmx = fmaxf(kmx, kav[k]);
  float kp[KNB];
  float ks = 0.f;
#pragma unroll
  for (int k = 0; k < KNB; ++k) { kp[k] = expf(kav[k] - kmx); ks += kp[k]; }
  const float inv_ks = 1.f / ks;
#pragma unroll
  for (int k = 0; k < KNB; ++k) kp[k] *= inv_ks;
#pragma unroll
  for (int t = 0; t < 2; ++t) {
    const int d = tid + t * 256;
    float eNh = 0.f;
#pragma unroll
    for (int k = 0; k < KNB; ++k) eNh = fmaf(kp[k], sNb[k][d], eNh);
    const float e_ = eh[t];
    Ub[(size_t)node * DH + d] = f2bf(e_ + eNh);
    Vb[(size_t)node * DH + d] = f2bf(e_ * eNh);
  }
}

// a[n] = dot(hid_bf16[n], att2_w) + att2_b ; one wave per node
__global__ __launch_bounds__(256) void att_dot(const unsigned short* __restrict__ HIDb,
                                               const float* __restrict__ w2,
                                               const float* __restrict__ b2,
                                               float* __restrict__ a) {
  const int wid = threadIdx.x >> 6, lane = threadIdx.x & 63;
  const int node = blockIdx.x * 4 + wid;
  const ushort4 h4 = *reinterpret_cast<const ushort4*>(HIDb + (size_t)node * 256 + lane * 4);
  const float4 w4 = *reinterpret_cast<const float4*>(w2 + lane * 4);
  float s = bf2f(h4.x) * w4.x + bf2f(h4.y) * w4.y + bf2f(h4.z) * w4.z + bf2f(h4.w) * w4.w;
#pragma unroll
  for (int off = 32; off > 0; off >>= 1) s += __shfl_down(s, off, 64);
  if (lane == 0) a[node] = s + b2[0];
}

// global softmax stats over a[8192]
__global__ __launch_bounds__(1024) void softmax_stats(const float* __restrict__ a,
                                                      float* __restrict__ st) {
  __shared__ float red[16];
  __shared__ float bc;
  const int tid = threadIdx.x;
  float mx = -3.4e38f;
  for (int i = tid; i < N_NODES; i += 1024) mx = fmaxf(mx, a[i]);
#pragma unroll
  for (int off = 32; off > 0; off >>= 1) mx = fmaxf(mx, __shfl_xor(mx, off, 64));
  if ((tid & 63) == 0) red[tid >> 6] = mx;
  __syncthreads();
  if (tid == 0) {
    float m = red[0];
    for (int i = 1; i < 16; ++i) m = fmaxf(m, red[i]);
    bc = m;
  }
  __syncthreads();
  const float gm = bc;
  float se = 0.f;
  for (int i = tid; i < N_NODES; i += 1024) se += expf(a[i] - gm);
#pragma unroll
  for (int off = 32; off > 0; off >>= 1) se += __shfl_xor(se, off, 64);
  if ((tid & 63) == 0) red[tid >> 6] = se;
  __syncthreads();
  if (tid == 0) {
    float s = 0.f;
    for (int i = 0; i < 16; ++i) s += red[i];
    st[0] = gm;
    st[1] = s;
  }
}

// h[c] = sum_n softmax(a)_n * emb_bf16[n][c]
__global__ __launch_bounds__(256) void readout(const unsigned short* __restrict__ EMBb,
                                               const float* __restrict__ a,
                                               const float* __restrict__ st,
                                               float* __restrict__ h) {
  __shared__ float sacc[4][64];
  const int tid = threadIdx.x;
  const int c = (blockIdx.x << 6) + (tid & 63);
  const int rsub = tid >> 6;
  const float mx = st[0], inv_se = 1.f / st[1];
  const int r0 = blockIdx.y << 8;
  float acc = 0.f;
  for (int i = 0; i < 64; ++i) {
    const int r = r0 + (i << 2) + rsub;
    const float g = expf(a[r] - mx);
    acc = fmaf(g, bf2f(EMBb[(size_t)r * DH + c]), acc);
  }
  sacc[rsub][tid & 63] = acc * inv_se;
  __syncthreads();
  if (rsub == 0) {
    float t = sacc[0][tid] + sacc[1][tid] + sacc[2][tid] + sacc[3][tid];
    atomicAdd(&h[c], t);
  }
}

// layernorm + final fc -> 2 logits
__global__ __launch_bounds__(512) void finalize(const float* __restrict__ h,
                                                const float* __restrict__ ln_g,
                                                const float* __restrict__ ln_b,
                                                const float* __restrict__ fc_w,
                                                const float* __restrict__ fc_b,
                                                float* __restrict__ out) {
  __shared__ float red0[8];
  __shared__ float red1[8];
  __shared__ float bc[2];
  const int tid = threadIdx.x;
  const int wid = tid >> 6, lane = tid & 63;
  const float v = h[tid];
  float s = v;
#pragma unroll
  for (int off = 32; off > 0; off >>= 1) s += __shfl_xor(s, off, 64);
  if (lane == 0) red0[wid] = s;
  __syncthreads();
  if (tid == 0) {
    float t = 0.f;
    for (int i = 0; i < 8; ++i) t += red0[i];
    bc[0] = t * (1.f / 512.f);
  }
  __syncthreads();
  const float mu = bc[0];
  const float dv = v - mu;
  s = dv * dv;
#pragma unroll
  for (int off = 32; off > 0; off >>= 1) s += __shfl_xor(s, off, 64);
  if (lane == 0) red0[wid] = s;
  __syncthreads();
  if (tid == 0) {
    float t = 0.f;
    for (int i = 0; i < 8; ++i) t += red0[i];
    bc[1] = t * (1.f / 512.f);
  }
  __syncthreads();
  const float var = bc[1];
  const float hn = dv / sqrtf(var + 1e-5f) * ln_g[tid] + ln_b[tid];
  float l0 = hn * fc_w[tid * 2 + 0];
  float l1 = hn * fc_w[tid * 2 + 1];
#pragma unroll
  for (int off = 32; off > 0; off >>= 1) {
    l0 += __shfl_xor(l0, off, 64);
    l1 += __shfl_xor(l1, off, 64);
  }
  if (lane == 0) { red0[wid] = l0; red1[wid] = l1; }
  __syncthreads();
  if (tid == 0) {
    float t0 = 0.f, t1 = 0.f;
    for (int i = 0; i < 8; ++i) { t0 += red0[i]; t1 += red1[i]; }
    out[0] = t0 + fc_b[0];
    out[1] = t1 + fc_b[1];
  }
}

// ---------------------------------------------------------------------------
extern "C" void kernel_launch(void* const* d_in, const int* in_sizes, int n_in,
                              void* d_out, int out_size, void* d_ws, size_t ws_size,
                              hipStream_t stream) {
  const float* x_s    = (const float*)d_in[0];
  const float* fc1_w  = (const float*)d_in[1];
  const float* fc1_b  = (const float*)d_in[2];
  const float* wh_w   = (const float*)d_in[3];
  const float* wh_b   = (const float*)d_in[4];
  const float* wt_w   = (const float*)d_in[5];
  const float* wt_b   = (const float*)d_in[6];
  const float* l1_w   = (const float*)d_in[7];
  const float* l1_b   = (const float*)d_in[8];
  const float* l2_w   = (const float*)d_in[9];
  const float* l2_b   = (const float*)d_in[10];
  const float* att1_w = (const float*)d_in[11];
  const float* att1_b = (const float*)d_in[12];
  const float* att2_w = (const float*)d_in[13];
  const float* att2_b = (const float*)d_in[14];
  const float* ln_g   = (const float*)d_in[15];
  const float* ln_b   = (const float*)d_in[16];
  const float* fc_w   = (const float*)d_in[17];
  const float* fc_b   = (const float*)d_in[18];

  float* ws = (float*)d_ws;
  const size_t BIG = (size_t)N_NODES * DH;  // 4,194,304
  float* B1 = ws;                                        // x fp32 (fc1 out)
  unsigned short* R1 = (unsigned short*)(ws + BIG);      // xsb -> EHb -> embb
  unsigned short* R2 = R1 + BIG;                          // xb  -> Ub  -> hidb
  unsigned short* R3 = R2 + BIG;                          // ETp -> Vb
  unsigned short* R4 = R3 + BIG;                          // ETb (row-major)
  unsigned short* WT = R4 + BIG;                          // transposed bf16 weights
  float* tail = (float*)(WT + 1376256);
  float* tkv    = tail;                          // 4*8192*6
  int*   tki    = (int*)(tkv + NSPLIT * N_NODES * 6);
  float* fwv    = (float*)(tki + NSPLIT * N_NODES * 6);
  int*   fiv    = (int*)(fwv + N_NODES * 6);
  float* colsum = (float*)(fiv + N_NODES * 6);
  float* av     = colsum + DH;
  float* stats  = av + N_NODES;
  float* hbuf   = stats + 16;

  unsigned short* fc1t  = WT + 0;
  unsigned short* wht   = WT + 196608;
  unsigned short* wtt   = WT + 458752;
  unsigned short* l1t   = WT + 720896;
  unsigned short* l2t   = WT + 983040;
  unsigned short* att1t = WT + 1245184;

  // 0. prep (LDS tile-transpose, coalesced both sides)
  prep_weights_t<<<336, 256, 0, stream>>>(fc1_w, wh_w, wt_w, l1_w, l2_w, att1_w, WT);
  convert_xs<<<3072, 256, 0, stream>>>(x_s, R1);
  // 1. x = lrelu(xsb @ fc1t^T + b) -> B1 fp32
  gemm128<1, 1, 0><<<dim3(4, 64), 512, 0, stream>>>(
      R1, fc1t, fc1_b, B1, nullptr, DIN, DH);
  // 2. mean-mix -> xb bf16 (R2)
  hipMemsetAsync(colsum, 0, DH * sizeof(float), stream);
  colsum_kernel<<<64, 256, 0, stream>>>(B1, colsum);
  mix_kernel<<<4096, 256, 0, stream>>>(B1, colsum, R2);
  // 3. fused e_h/e_t -> EHb (R1, unscaled), ETp (R3), ETb (R4); no fp32 out
  gemm128_ehet<<<dim3(4, 64), 512, 0, stream>>>(
      R2, wht, wtt, wh_b, wt_b, R1, R3, R4);
  // 4. scoring (r9-proven v6) + merge (applies kscale)
  score_topk_v6<<<1024, 256, 0, stream>>>(R1, R3, tkv, tki);
  merge_topk4<<<32, 256, 0, stream>>>(tkv, tki, fwv, fiv);
  // 5. aggregation (all-bf16 inputs) -> Ub (R2), Vb (R3)
  agg_kernel<<<N_NODES, 256, 0, stream>>>(R1, R4, fwv, fiv, R2, R3);
  // 6. fused l1/l2 -> embb (R1)
  gemm128_l1l2<<<dim3(4, 64), 512, 0, stream>>>(
      R2, R3, l1t, l2t, l1_b, l2_b, R1);
  // 7. attention readout: hid = lrelu(embb@att1+b) -> hidb (R2)
  gemm128<1, 0, 1><<<dim3(2, 64), 512, 0, stream>>>(
      R1, att1t, att1_b, nullptr, R2, DH, 256);
  att_dot<<<2048, 256, 0, stream>>>(R2, att2_w, att2_b, av);
  softmax_stats<<<1, 1024, 0, stream>>>(av, stats);
  hipMemsetAsync(hbuf, 0, DH * sizeof(float), stream);
  readout<<<dim3(8, 32), 256, 0, stream>>>(R1, av, stats, hbuf);
  // 8. layernorm + logits
  finalize<<<1, 512, 0, stream>>>(hbuf, ln_g, ln_b, fc_w, fc_b, (float*)d_out);
}